// Round 1
// baseline (2217.382 us; speedup 1.0000x reference)
//
#include <hip/hip_runtime.h>
#include <math.h>

// MKAFullAttention: B=4, T=1024, D=1024, H=16, DH=64, BETA=0.9
// Round 1: all-f32 correctness baseline.
//   - l3 stream is analytically attend(l3) = broadcast(l3@wv) (uniform causal
//     softmax over identical keys/values) -> no k3, no attention pass 3.
//   - EMA via 3-phase chunked scan (64-step chunks).
// Workspace layout (floats):
//   q[4M] | l2[4M] | k[4M] | v[4M] | mixed[4M] | hdnp[2M] | v3[4096] | g[64K]
//   total ~92.6 MB.

#define B_ 4
#define T_ 1024
#define D_ 1024
#define H_ 16
#define DH_ 64
#define M_ 4096

#define ECH 64
#define NCH 16

// ---------------- EMA chunked scan ----------------
__global__ __launch_bounds__(256) void ema_chunk_kernel(const float* __restrict__ x,
                                                        float* __restrict__ l2) {
  int idx = blockIdx.x * 256 + threadIdx.x;  // B*NCH*D = 65536
  int d = idx & (D_ - 1);
  int ch = (idx >> 10) & (NCH - 1);
  int b = idx >> 14;
  const float* xp = x + (size_t)(b * T_ + ch * ECH) * D_ + d;
  float* yp = l2 + (size_t)(b * T_ + ch * ECH) * D_ + d;
  float y = 0.f;
#pragma unroll 4
  for (int t = 0; t < ECH; ++t) {
    y = 0.9f * y + 0.1f * xp[t * D_];
    yp[t * D_] = y;
  }
}

__global__ __launch_bounds__(256) void ema_carry_kernel(const float* __restrict__ l2,
                                                        float* __restrict__ g) {
  int idx = blockIdx.x * 256 + threadIdx.x;  // B*D = 4096
  int d = idx & (D_ - 1);
  int b = idx >> 10;
  const float b64 = 0.0011790184577739f;  // 0.9^64
  float G = 0.f;
  for (int ch = 0; ch < NCH; ++ch) {
    g[(size_t)(b * NCH + ch) * D_ + d] = G;  // carry-in for chunk ch
    float lf = l2[(size_t)(b * T_ + ch * ECH + ECH - 1) * D_ + d];
    G = lf + b64 * G;
  }
}

__global__ __launch_bounds__(256) void ema_fix_kernel(float* __restrict__ l2,
                                                      const float* __restrict__ g) {
  int idx = blockIdx.x * 256 + threadIdx.x;  // 4M
  int d = idx & (D_ - 1);
  int t = (idx >> 10) & (T_ - 1);
  int b = idx >> 20;
  int ch = t >> 6;
  int off = t & (ECH - 1);
  float G = g[(size_t)(b * NCH + ch) * D_ + d];
  l2[idx] += powf(0.9f, (float)(off + 1)) * G;
}

// ---------------- generic f32 GEMM: C[M,N] = A[M,K] @ B[K,N] ----------------
// 64x64 tile, BK=16, 256 threads, 4x4 per thread.
__global__ __launch_bounds__(256) void gemm_f32(const float* __restrict__ A,
                                                const float* __restrict__ Bm,
                                                float* __restrict__ C, int Ndim, int Kdim) {
  __shared__ float As[16][68];  // [k][m], stride 68 keeps float4 rows 16B-aligned
  __shared__ float Bs[16][68];  // [k][n]
  int tid = threadIdx.x;
  int tx = tid & 15;  // col group
  int ty = tid >> 4;  // row group
  int row0 = blockIdx.y * 64;
  int col0 = blockIdx.x * 64;
  float acc[4][4] = {};
  for (int k0 = 0; k0 < Kdim; k0 += 16) {
#pragma unroll
    for (int it = 0; it < 4; ++it) {
      int i = tid + it * 256;
      int r = i >> 4;
      int kk = i & 15;
      As[kk][r] = A[(size_t)(row0 + r) * Kdim + k0 + kk];
    }
#pragma unroll
    for (int it = 0; it < 4; ++it) {
      int i = tid + it * 256;
      int kk = i >> 6;
      int c = i & 63;
      Bs[kk][c] = Bm[(size_t)(k0 + kk) * Ndim + col0 + c];
    }
    __syncthreads();
#pragma unroll
    for (int kk = 0; kk < 16; ++kk) {
      float4 av = *(const float4*)&As[kk][ty * 4];
      float4 bv = *(const float4*)&Bs[kk][tx * 4];
      float a[4] = {av.x, av.y, av.z, av.w};
      float b[4] = {bv.x, bv.y, bv.z, bv.w};
#pragma unroll
      for (int i2 = 0; i2 < 4; ++i2)
#pragma unroll
        for (int j = 0; j < 4; ++j) acc[i2][j] += a[i2] * b[j];
    }
    __syncthreads();
  }
#pragma unroll
  for (int i2 = 0; i2 < 4; ++i2)
#pragma unroll
    for (int j = 0; j < 4; ++j)
      C[(size_t)(row0 + ty * 4 + i2) * Ndim + col0 + tx * 4 + j] = acc[i2][j];
}

// ---------------- v3 = l3_memory @ wv  ([B,1024]) ----------------
__global__ __launch_bounds__(256) void v3_kernel(const float* __restrict__ l3,
                                                 const float* __restrict__ wv,
                                                 float* __restrict__ v3) {
  int idx = blockIdx.x * 256 + threadIdx.x;  // B*D = 4096
  int b = idx >> 10;
  int col = idx & 1023;
  const float* xr = l3 + (size_t)b * D_;
  float acc = 0.f;
#pragma unroll 8
  for (int k = 0; k < D_; ++k) acc += xr[k] * wv[(size_t)k * D_ + col];
  v3[idx] = acc;
}

// ---------------- router: lam = softmax(gelu(hdnp + rb1) @ rw2 + rb2) ----------------
__global__ __launch_bounds__(256) void router_kernel(const float* __restrict__ hdnp,
                                                     const float* __restrict__ rb1,
                                                     const float* __restrict__ rw2,
                                                     const float* __restrict__ rb2,
                                                     float* __restrict__ lam) {
  int wave = (blockIdx.x * 256 + threadIdx.x) >> 6;  // row, 4096 total
  int lane = threadIdx.x & 63;
  const float* hr = hdnp + (size_t)wave * 512;
  float s0 = 0.f, s1 = 0.f, s2 = 0.f;
#pragma unroll
  for (int u = 0; u < 8; ++u) {
    int hcol = u * 64 + lane;
    float vv = hr[hcol] + rb1[hcol];
    float gl = 0.5f * vv * (1.0f + erff(vv * 0.70710678118654752f));
    s0 += gl * rw2[hcol * 3 + 0];
    s1 += gl * rw2[hcol * 3 + 1];
    s2 += gl * rw2[hcol * 3 + 2];
  }
#pragma unroll
  for (int off = 32; off; off >>= 1) {
    s0 += __shfl_xor(s0, off);
    s1 += __shfl_xor(s1, off);
    s2 += __shfl_xor(s2, off);
  }
  if (lane == 0) {
    float a = s0 + rb2[0], bb = s1 + rb2[1], c = s2 + rb2[2];
    float m = fmaxf(fmaxf(a, bb), c);
    float e0 = expf(a - m), e1 = expf(bb - m), e2 = expf(c - m);
    float inv = 1.0f / (e0 + e1 + e2);
    lam[(size_t)wave * 3 + 0] = e0 * inv;
    lam[(size_t)wave * 3 + 1] = e1 * inv;
    lam[(size_t)wave * 3 + 2] = e2 * inv;
  }
}

// ---------------- mixed init: lam[...,2] * broadcast(v3) ----------------
__global__ __launch_bounds__(256) void init_mixed_kernel(const float* __restrict__ lam,
                                                         const float* __restrict__ v3,
                                                         float* __restrict__ mixed) {
  int idx = blockIdx.x * 256 + threadIdx.x;  // B*H*T*DH = 4M
  int i = idx & 63;
  int t = (idx >> 6) & 1023;
  int h = (idx >> 16) & 15;
  int b = idx >> 20;
  mixed[idx] = lam[(size_t)((b << 10) + t) * 3 + 2] * v3[(b << 10) + (h << 6) + i];
}

// ---------------- causal attention, accumulate lam-weighted into mixed ----------------
// One block = one (b,h) and 8 q-rows. S kept in LDS, softmax exact two-pass.
__global__ __launch_bounds__(256) void attn_kernel(const float* __restrict__ q,
                                                   const float* __restrict__ k,
                                                   const float* __restrict__ v,
                                                   const float* __restrict__ lam, int lamcol,
                                                   float* __restrict__ mixed) {
  __shared__ float S[8][1025];
  __shared__ float qs[8][66];
  __shared__ float kv[32][66];
  int bh = blockIdx.y;
  int b = bh >> 4, h = bh & 15;
  int r0 = blockIdx.x * 8;
  int tid = threadIdx.x;
  {
    int r = tid >> 6, i = tid & 63;
    qs[r][i] = q[(size_t)(b * T_ + r0 + r) * D_ + h * DH_ + i];
    qs[r + 4][i] = q[(size_t)(b * T_ + r0 + r + 4) * D_ + h * DH_ + i];
  }
  int tmax = r0 + 7;
  int ntiles = (tmax >> 5) + 1;
  int sr = tid >> 5;   // q-row 0..7
  int sj = tid & 31;   // key-in-tile
  int t_r = r0 + sr;
  // ---- scores ----
  for (int kt = 0; kt < ntiles; ++kt) {
    __syncthreads();
#pragma unroll
    for (int it = 0; it < 8; ++it) {
      int e = tid + it * 256;
      int row = e >> 6, i = e & 63;
      kv[row][i] = k[(size_t)(b * T_ + kt * 32 + row) * D_ + h * DH_ + i];
    }
    __syncthreads();
    int j = kt * 32 + sj;
    if (j <= t_r) {
      float acc = 0.f;
#pragma unroll
      for (int i = 0; i < 64; ++i) acc += qs[sr][i] * kv[sj][i];
      S[sr][j] = acc * 0.125f;
    }
  }
  __syncthreads();
  // ---- softmax (32 threads per row; same-wave lockstep) ----
  int l = tid & 31;
  int cnt = t_r + 1;
  float m = -1e30f;
  for (int j = l; j < cnt; j += 32) m = fmaxf(m, S[sr][j]);
#pragma unroll
  for (int off = 16; off; off >>= 1) m = fmaxf(m, __shfl_xor(m, off));
  float sum = 0.f;
  for (int j = l; j < cnt; j += 32) {
    float e = expf(S[sr][j] - m);
    S[sr][j] = e;
    sum += e;
  }
#pragma unroll
  for (int off = 16; off; off >>= 1) sum += __shfl_xor(sum, off);
  float inv = 1.0f / sum;
  // ---- PV ----
  float acc0 = 0.f, acc1 = 0.f;
  int i0 = (tid & 31) * 2;
  for (int kt = 0; kt < ntiles; ++kt) {
    __syncthreads();
#pragma unroll
    for (int it = 0; it < 8; ++it) {
      int e = tid + it * 256;
      int row = e >> 6, i = e & 63;
      kv[row][i] = v[(size_t)(b * T_ + kt * 32 + row) * D_ + h * DH_ + i];
    }
    __syncthreads();
    int jend = cnt - kt * 32;
    if (jend > 32) jend = 32;
    for (int jj = 0; jj < jend; ++jj) {
      float p = S[sr][kt * 32 + jj];
      float2 vv = *(const float2*)&kv[jj][i0];
      acc0 += p * vv.x;
      acc1 += p * vv.y;
    }
  }
  float lamv = lam[(size_t)(b * T_ + t_r) * 3 + lamcol] * inv;
  size_t om = (size_t)((b * H_ + h) * T_ + t_r) * DH_ + i0;
  mixed[om] += lamv * acc0;
  mixed[om + 1] += lamv * acc1;
}

// ---------------- merge heads: [b,h,t,dh] -> [b,t,d] ----------------
__global__ __launch_bounds__(256) void merge_heads_kernel(const float* __restrict__ mixed,
                                                          float* __restrict__ merged) {
  int idx = blockIdx.x * 256 + threadIdx.x;  // 4M, output order
  int d = idx & 1023;
  int t = (idx >> 10) & 1023;
  int b = idx >> 20;
  int h = d >> 6, i = d & 63;
  merged[idx] = mixed[(size_t)((b * H_ + h) * T_ + t) * DH_ + i];
}

extern "C" void kernel_launch(void* const* d_in, const int* in_sizes, int n_in,
                              void* d_out, int out_size, void* d_ws, size_t ws_size,
                              hipStream_t stream) {
  const float* x = (const float*)d_in[0];
  const float* l3m = (const float*)d_in[1];
  const float* wq = (const float*)d_in[2];
  const float* wk = (const float*)d_in[3];
  const float* wv = (const float*)d_in[4];
  const float* wo = (const float*)d_in[5];
  const float* rw1 = (const float*)d_in[6];
  const float* rb1 = (const float*)d_in[7];
  const float* rw2 = (const float*)d_in[8];
  const float* rb2 = (const float*)d_in[9];

  float* out = (float*)d_out;
  float* lam = out + (size_t)M_ * D_;  // output tail: [4096,3]

  float* ws = (float*)d_ws;
  float* q = ws;
  float* l2 = ws + (size_t)4194304;
  float* kbuf = ws + (size_t)8388608;
  float* vbuf = ws + (size_t)12582912;
  float* mixed = ws + (size_t)16777216;
  float* hdnp = ws + (size_t)20971520;
  float* v3 = ws + (size_t)23068672;
  float* gbuf = ws + (size_t)23072768;

  dim3 blk(256);
  dim3 gemm_grid(16, 64);   // N=1024
  dim3 gemm_grid_r(8, 64);  // N=512

  // EMA l2
  ema_chunk_kernel<<<256, blk, 0, stream>>>(x, l2);
  ema_carry_kernel<<<16, blk, 0, stream>>>(l2, gbuf);
  ema_fix_kernel<<<16384, blk, 0, stream>>>(l2, gbuf);

  // q = x @ wq
  gemm_f32<<<gemm_grid, blk, 0, stream>>>(x, wq, q, 1024, 1024);
  // router
  gemm_f32<<<gemm_grid_r, blk, 0, stream>>>(q, rw1, hdnp, 512, 1024);
  router_kernel<<<1024, blk, 0, stream>>>(hdnp, rb1, rw2, rb2, lam);
  // l3 value vector + mixed init
  v3_kernel<<<16, blk, 0, stream>>>(l3m, wv, v3);
  init_mixed_kernel<<<16384, blk, 0, stream>>>(lam, v3, mixed);

  // stream 0: mem = x
  gemm_f32<<<gemm_grid, blk, 0, stream>>>(x, wk, kbuf, 1024, 1024);
  gemm_f32<<<gemm_grid, blk, 0, stream>>>(x, wv, vbuf, 1024, 1024);
  attn_kernel<<<dim3(128, 64), blk, 0, stream>>>(q, kbuf, vbuf, lam, 0, mixed);

  // stream 1: mem = l2
  gemm_f32<<<gemm_grid, blk, 0, stream>>>(l2, wk, kbuf, 1024, 1024);
  gemm_f32<<<gemm_grid, blk, 0, stream>>>(l2, wv, vbuf, 1024, 1024);
  attn_kernel<<<dim3(128, 64), blk, 0, stream>>>(q, kbuf, vbuf, lam, 1, mixed);

  // out = merge(mixed) @ wo   (reuse l2 buffer for merged)
  merge_heads_kernel<<<16384, blk, 0, stream>>>(mixed, l2);
  gemm_f32<<<gemm_grid, blk, 0, stream>>>(l2, wo, out, 1024, 1024);
}

// Round 2
// 1301.349 us; speedup vs baseline: 1.7039x; 1.7039x over previous
//
#include <hip/hip_runtime.h>
#include <hip/hip_bf16.h>
#include <math.h>

// MKAFullAttention: B=4, T=1024, D=1024, H=16, DH=64, BETA=0.9
// Round 2: MFMA (bf16) flash attention; GEMMs still f32 (next round).
//   - l3 stream analytic: attend(l3) = broadcast(l3@wv).
//   - mixed kept in [b,t,d] layout; merge_heads eliminated.

#define B_ 4
#define T_ 1024
#define D_ 1024
#define H_ 16
#define DH_ 64
#define M_ 4096

#define ECH 64
#define NCH 16

typedef __attribute__((ext_vector_type(8))) short bf16x8;
typedef __attribute__((ext_vector_type(4))) float f32x4;

__device__ inline short f2b(float f) {
  __hip_bfloat16 h = __float2bfloat16(f);
  return *reinterpret_cast<short*>(&h);
}

// ---------------- EMA chunked scan ----------------
__global__ __launch_bounds__(256) void ema_chunk_kernel(const float* __restrict__ x,
                                                        float* __restrict__ l2) {
  int idx = blockIdx.x * 256 + threadIdx.x;  // B*NCH*D = 65536
  int d = idx & (D_ - 1);
  int ch = (idx >> 10) & (NCH - 1);
  int b = idx >> 14;
  const float* xp = x + (size_t)(b * T_ + ch * ECH) * D_ + d;
  float* yp = l2 + (size_t)(b * T_ + ch * ECH) * D_ + d;
  float y = 0.f;
#pragma unroll 4
  for (int t = 0; t < ECH; ++t) {
    y = 0.9f * y + 0.1f * xp[t * D_];
    yp[t * D_] = y;
  }
}

__global__ __launch_bounds__(256) void ema_carry_kernel(const float* __restrict__ l2,
                                                        float* __restrict__ g) {
  int idx = blockIdx.x * 256 + threadIdx.x;  // B*D = 4096
  int d = idx & (D_ - 1);
  int b = idx >> 10;
  const float b64 = 0.0011790184577739f;  // 0.9^64
  float G = 0.f;
  for (int ch = 0; ch < NCH; ++ch) {
    g[(size_t)(b * NCH + ch) * D_ + d] = G;
    float lf = l2[(size_t)(b * T_ + ch * ECH + ECH - 1) * D_ + d];
    G = lf + b64 * G;
  }
}

__global__ __launch_bounds__(256) void ema_fix_kernel(float* __restrict__ l2,
                                                      const float* __restrict__ g) {
  int idx = blockIdx.x * 256 + threadIdx.x;  // 4M
  int d = idx & (D_ - 1);
  int t = (idx >> 10) & (T_ - 1);
  int b = idx >> 20;
  int ch = t >> 6;
  int off = t & (ECH - 1);
  float G = g[(size_t)(b * NCH + ch) * D_ + d];
  l2[idx] += powf(0.9f, (float)(off + 1)) * G;
}

// ---------------- generic f32 GEMM: C[M,N] = A[M,K] @ B[K,N] ----------------
__global__ __launch_bounds__(256) void gemm_f32(const float* __restrict__ A,
                                                const float* __restrict__ Bm,
                                                float* __restrict__ C, int Ndim, int Kdim) {
  __shared__ float As[16][68];
  __shared__ float Bs[16][68];
  int tid = threadIdx.x;
  int tx = tid & 15;
  int ty = tid >> 4;
  int row0 = blockIdx.y * 64;
  int col0 = blockIdx.x * 64;
  float acc[4][4] = {};
  for (int k0 = 0; k0 < Kdim; k0 += 16) {
#pragma unroll
    for (int it = 0; it < 4; ++it) {
      int i = tid + it * 256;
      int r = i >> 4;
      int kk = i & 15;
      As[kk][r] = A[(size_t)(row0 + r) * Kdim + k0 + kk];
    }
#pragma unroll
    for (int it = 0; it < 4; ++it) {
      int i = tid + it * 256;
      int kk = i >> 6;
      int c = i & 63;
      Bs[kk][c] = Bm[(size_t)(k0 + kk) * Ndim + col0 + c];
    }
    __syncthreads();
#pragma unroll
    for (int kk = 0; kk < 16; ++kk) {
      float4 av = *(const float4*)&As[kk][ty * 4];
      float4 bv = *(const float4*)&Bs[kk][tx * 4];
      float a[4] = {av.x, av.y, av.z, av.w};
      float b[4] = {bv.x, bv.y, bv.z, bv.w};
#pragma unroll
      for (int i2 = 0; i2 < 4; ++i2)
#pragma unroll
        for (int j = 0; j < 4; ++j) acc[i2][j] += a[i2] * b[j];
    }
    __syncthreads();
  }
#pragma unroll
  for (int i2 = 0; i2 < 4; ++i2)
#pragma unroll
    for (int j = 0; j < 4; ++j)
      C[(size_t)(row0 + ty * 4 + i2) * Ndim + col0 + tx * 4 + j] = acc[i2][j];
}

// ---------------- v3 = l3_memory @ wv  ([B,1024]) ----------------
__global__ __launch_bounds__(256) void v3_kernel(const float* __restrict__ l3,
                                                 const float* __restrict__ wv,
                                                 float* __restrict__ v3) {
  int idx = blockIdx.x * 256 + threadIdx.x;  // B*D = 4096
  int b = idx >> 10;
  int col = idx & 1023;
  const float* xr = l3 + (size_t)b * D_;
  float acc = 0.f;
#pragma unroll 8
  for (int k = 0; k < D_; ++k) acc += xr[k] * wv[(size_t)k * D_ + col];
  v3[idx] = acc;
}

// ---------------- router ----------------
__global__ __launch_bounds__(256) void router_kernel(const float* __restrict__ hdnp,
                                                     const float* __restrict__ rb1,
                                                     const float* __restrict__ rw2,
                                                     const float* __restrict__ rb2,
                                                     float* __restrict__ lam) {
  int wave = (blockIdx.x * 256 + threadIdx.x) >> 6;
  int lane = threadIdx.x & 63;
  const float* hr = hdnp + (size_t)wave * 512;
  float s0 = 0.f, s1 = 0.f, s2 = 0.f;
#pragma unroll
  for (int u = 0; u < 8; ++u) {
    int hcol = u * 64 + lane;
    float vv = hr[hcol] + rb1[hcol];
    float gl = 0.5f * vv * (1.0f + erff(vv * 0.70710678118654752f));
    s0 += gl * rw2[hcol * 3 + 0];
    s1 += gl * rw2[hcol * 3 + 1];
    s2 += gl * rw2[hcol * 3 + 2];
  }
#pragma unroll
  for (int off = 32; off; off >>= 1) {
    s0 += __shfl_xor(s0, off);
    s1 += __shfl_xor(s1, off);
    s2 += __shfl_xor(s2, off);
  }
  if (lane == 0) {
    float a = s0 + rb2[0], bb = s1 + rb2[1], c = s2 + rb2[2];
    float m = fmaxf(fmaxf(a, bb), c);
    float e0 = expf(a - m), e1 = expf(bb - m), e2 = expf(c - m);
    float inv = 1.0f / (e0 + e1 + e2);
    lam[(size_t)wave * 3 + 0] = e0 * inv;
    lam[(size_t)wave * 3 + 1] = e1 * inv;
    lam[(size_t)wave * 3 + 2] = e2 * inv;
  }
}

// ---------------- mixed init (in [b,t,d] layout): lam[...,2] * broadcast(v3) ----------------
__global__ __launch_bounds__(256) void init_mixed_kernel(const float* __restrict__ lam,
                                                         const float* __restrict__ v3,
                                                         float* __restrict__ mixed) {
  int idx = blockIdx.x * 256 + threadIdx.x;  // 4M
  int d = idx & 1023;
  int t = (idx >> 10) & 1023;
  int b = idx >> 20;
  mixed[idx] = lam[(size_t)(b * T_ + t) * 3 + 2] * v3[(b << 10) + d];
}

// ---------------- MFMA flash attention, accumulate lam-weighted into mixed[b,t,d] ----------------
// Block: 64 q-rows of one (b,h); 4 waves x 16 rows. K-tiles of 32 keys.
__global__ __launch_bounds__(256) void attn_mfma_kernel(const float* __restrict__ q,
                                                        const float* __restrict__ k,
                                                        const float* __restrict__ v,
                                                        const float* __restrict__ lam, int lamcol,
                                                        float* __restrict__ mixed) {
  __shared__ short Qs[64][72];      // [qrow][dh], 144B stride (16B-aligned)
  __shared__ short Ks[32][72];      // [key][dh]
  __shared__ short Vt[64][40];      // [dh][key], 80B stride
  __shared__ short Ps[4][16][40];   // per-wave P tile [qrow][key]

  int bh = blockIdx.y;
  int b = bh >> 4, h = bh & 15;
  int q0 = blockIdx.x * 64;
  int tid = threadIdx.x;
  int w = tid >> 6, l = tid & 63;
  int lg = l >> 4;   // 0..3
  int ll = l & 15;   // 0..15

  // stage Q tile (f32 -> bf16)
#pragma unroll
  for (int it = 0; it < 16; ++it) {
    int e = it * 256 + tid;
    int r = e >> 6, dh = e & 63;
    Qs[r][dh] = f2b(q[(size_t)(b * T_ + q0 + r) * D_ + h * DH_ + dh]);
  }
  __syncthreads();

  bf16x8 qf0 = *(const bf16x8*)&Qs[w * 16 + ll][lg * 8];
  bf16x8 qf1 = *(const bf16x8*)&Qs[w * 16 + ll][32 + lg * 8];

  float m_[4], l_[4];
  f32x4 o[4];
#pragma unroll
  for (int r = 0; r < 4; ++r) { m_[r] = -1e30f; l_[r] = 0.f; }
#pragma unroll
  for (int db = 0; db < 4; ++db) o[db] = (f32x4){0.f, 0.f, 0.f, 0.f};

  int qw0 = q0 + w * 16;
  int nt = (q0 + 64) >> 5;
  for (int kt = 0; kt < nt; ++kt) {
    __syncthreads();
    int key0 = kt * 32;
#pragma unroll
    for (int it = 0; it < 8; ++it) {
      int e = it * 256 + tid;
      int r = e >> 6, dh = e & 63;
      size_t gi = (size_t)(b * T_ + key0 + r) * D_ + h * DH_ + dh;
      Ks[r][dh] = f2b(k[gi]);
      Vt[dh][r] = f2b(v[gi]);
    }
    __syncthreads();
    if (key0 > qw0 + 15) continue;  // wave fully masked (uniform per wave)

    // ---- QK^T ----
    f32x4 c0 = (f32x4){0.f, 0.f, 0.f, 0.f}, c1 = (f32x4){0.f, 0.f, 0.f, 0.f};
    {
      bf16x8 kf0a = *(const bf16x8*)&Ks[ll][lg * 8];
      bf16x8 kf0b = *(const bf16x8*)&Ks[ll][32 + lg * 8];
      bf16x8 kf1a = *(const bf16x8*)&Ks[16 + ll][lg * 8];
      bf16x8 kf1b = *(const bf16x8*)&Ks[16 + ll][32 + lg * 8];
      c0 = __builtin_amdgcn_mfma_f32_16x16x32_bf16(qf0, kf0a, c0, 0, 0, 0);
      c0 = __builtin_amdgcn_mfma_f32_16x16x32_bf16(qf1, kf0b, c0, 0, 0, 0);
      c1 = __builtin_amdgcn_mfma_f32_16x16x32_bf16(qf0, kf1a, c1, 0, 0, 0);
      c1 = __builtin_amdgcn_mfma_f32_16x16x32_bf16(qf1, kf1b, c1, 0, 0, 0);
    }

    // ---- online softmax (rows = lg*4+r, cols = key0 + {ll, 16+ll}) ----
    float al[4];
#pragma unroll
    for (int r = 0; r < 4; ++r) {
      int row = qw0 + lg * 4 + r;
      float s0 = c0[r] * 0.125f, s1 = c1[r] * 0.125f;
      if (key0 + ll > row) s0 = -1e30f;
      if (key0 + 16 + ll > row) s1 = -1e30f;
      float mx = fmaxf(s0, s1);
      mx = fmaxf(mx, __shfl_xor(mx, 1));
      mx = fmaxf(mx, __shfl_xor(mx, 2));
      mx = fmaxf(mx, __shfl_xor(mx, 4));
      mx = fmaxf(mx, __shfl_xor(mx, 8));
      float nm = fmaxf(m_[r], mx);
      al[r] = expf(m_[r] - nm);
      float p0 = expf(s0 - nm);
      float p1 = expf(s1 - nm);
      float rs = p0 + p1;
      rs += __shfl_xor(rs, 1);
      rs += __shfl_xor(rs, 2);
      rs += __shfl_xor(rs, 4);
      rs += __shfl_xor(rs, 8);
      l_[r] = l_[r] * al[r] + rs;
      m_[r] = nm;
      Ps[w][lg * 4 + r][ll] = f2b(p0);
      Ps[w][lg * 4 + r][16 + ll] = f2b(p1);
    }
#pragma unroll
    for (int db = 0; db < 4; ++db)
#pragma unroll
      for (int r = 0; r < 4; ++r) o[db][r] *= al[r];

    // wave-private P write -> read: ensure LDS ops complete
    asm volatile("s_waitcnt lgkmcnt(0)" ::: "memory");

    // ---- PV ----
    bf16x8 pf = *(const bf16x8*)&Ps[w][ll][lg * 8];
#pragma unroll
    for (int db = 0; db < 4; ++db) {
      bf16x8 vf = *(const bf16x8*)&Vt[db * 16 + ll][lg * 8];
      o[db] = __builtin_amdgcn_mfma_f32_16x16x32_bf16(pf, vf, o[db], 0, 0, 0);
    }
  }

  // ---- epilogue: *lam/l, accumulate into mixed[b,t,d] ----
#pragma unroll
  for (int r = 0; r < 4; ++r) {
    int row = qw0 + lg * 4 + r;
    float lamv = lam[(size_t)(b * T_ + row) * 3 + lamcol] / l_[r];
#pragma unroll
    for (int db = 0; db < 4; ++db) {
      size_t oi = (size_t)(b * T_ + row) * D_ + h * DH_ + db * 16 + ll;
      mixed[oi] += lamv * o[db][r];
    }
  }
}

extern "C" void kernel_launch(void* const* d_in, const int* in_sizes, int n_in,
                              void* d_out, int out_size, void* d_ws, size_t ws_size,
                              hipStream_t stream) {
  const float* x = (const float*)d_in[0];
  const float* l3m = (const float*)d_in[1];
  const float* wq = (const float*)d_in[2];
  const float* wk = (const float*)d_in[3];
  const float* wv = (const float*)d_in[4];
  const float* wo = (const float*)d_in[5];
  const float* rw1 = (const float*)d_in[6];
  const float* rb1 = (const float*)d_in[7];
  const float* rw2 = (const float*)d_in[8];
  const float* rb2 = (const float*)d_in[9];

  float* out = (float*)d_out;
  float* lam = out + (size_t)M_ * D_;  // output tail: [4096,3]

  float* ws = (float*)d_ws;
  float* q = ws;
  float* l2 = ws + (size_t)4194304;
  float* kbuf = ws + (size_t)8388608;
  float* vbuf = ws + (size_t)12582912;
  float* mixed = ws + (size_t)16777216;
  float* hdnp = ws + (size_t)20971520;
  float* v3 = ws + (size_t)23068672;
  float* gbuf = ws + (size_t)23072768;

  dim3 blk(256);
  dim3 gemm_grid(16, 64);   // N=1024
  dim3 gemm_grid_r(8, 64);  // N=512
  dim3 attn_grid(16, 64);   // 16 q-blocks x (b,h)

  // EMA l2
  ema_chunk_kernel<<<256, blk, 0, stream>>>(x, l2);
  ema_carry_kernel<<<16, blk, 0, stream>>>(l2, gbuf);
  ema_fix_kernel<<<16384, blk, 0, stream>>>(l2, gbuf);

  // q = x @ wq
  gemm_f32<<<gemm_grid, blk, 0, stream>>>(x, wq, q, 1024, 1024);
  // router
  gemm_f32<<<gemm_grid_r, blk, 0, stream>>>(q, rw1, hdnp, 512, 1024);
  router_kernel<<<1024, blk, 0, stream>>>(hdnp, rb1, rw2, rb2, lam);
  // l3 value vector + mixed init
  v3_kernel<<<16, blk, 0, stream>>>(l3m, wv, v3);
  init_mixed_kernel<<<16384, blk, 0, stream>>>(lam, v3, mixed);

  // pass 0: mem = x
  gemm_f32<<<gemm_grid, blk, 0, stream>>>(x, wk, kbuf, 1024, 1024);
  gemm_f32<<<gemm_grid, blk, 0, stream>>>(x, wv, vbuf, 1024, 1024);
  attn_mfma_kernel<<<attn_grid, blk, 0, stream>>>(q, kbuf, vbuf, lam, 0, mixed);

  // pass 1: mem = l2
  gemm_f32<<<gemm_grid, blk, 0, stream>>>(l2, wk, kbuf, 1024, 1024);
  gemm_f32<<<gemm_grid, blk, 0, stream>>>(l2, wv, vbuf, 1024, 1024);
  attn_mfma_kernel<<<attn_grid, blk, 0, stream>>>(q, kbuf, vbuf, lam, 1, mixed);

  // out = mixed @ wo
  gemm_f32<<<gemm_grid, blk, 0, stream>>>(mixed, wo, out, 1024, 1024);
}

// Round 3
// 523.114 us; speedup vs baseline: 4.2388x; 2.4877x over previous
//
#include <hip/hip_runtime.h>
#include <hip/hip_bf16.h>
#include <math.h>

// MKAFullAttention: B=4, T=1024, D=1024, H=16, DH=64, BETA=0.9
// Round 3: all GEMMs -> bf16 MFMA (m97 structure: 128x128 tile, BK=64,
//          global_load_lds(16B) with pre-swizzled source + XOR-swizzled reads).
//          Attention unchanged except it now reads bf16 q/k/v directly.
//   - l3 stream analytic: attend(l3) = broadcast(l3@wv).
//   - mixed in [b,t,d] f32 (aliases dead l2-f32 region).

#define B_ 4
#define T_ 1024
#define D_ 1024
#define H_ 16
#define DH_ 64
#define M_ 4096

#define ECH 64
#define NCH 16

typedef __attribute__((ext_vector_type(8))) short bf16x8;
typedef __attribute__((ext_vector_type(4))) short s16x4;
typedef __attribute__((ext_vector_type(4))) float f32x4;

__device__ inline short f2b(float f) {
  __hip_bfloat16 h = __float2bfloat16(f);
  return *reinterpret_cast<short*>(&h);
}

__device__ inline void gload_lds16(const short* g, short* l) {
  __builtin_amdgcn_global_load_lds(
      (const __attribute__((address_space(1))) unsigned int*)g,
      (__attribute__((address_space(3))) unsigned int*)l, 16, 0, 0);
}

// ---------------- EMA chunked scan ----------------
__global__ __launch_bounds__(256) void ema_chunk_kernel(const float* __restrict__ x,
                                                        float* __restrict__ l2) {
  int idx = blockIdx.x * 256 + threadIdx.x;  // B*NCH*D = 65536
  int d = idx & (D_ - 1);
  int ch = (idx >> 10) & (NCH - 1);
  int b = idx >> 14;
  const float* xp = x + (size_t)(b * T_ + ch * ECH) * D_ + d;
  float* yp = l2 + (size_t)(b * T_ + ch * ECH) * D_ + d;
  float y = 0.f;
#pragma unroll 4
  for (int t = 0; t < ECH; ++t) {
    y = 0.9f * y + 0.1f * xp[t * D_];
    yp[t * D_] = y;
  }
}

__global__ __launch_bounds__(256) void ema_carry_kernel(const float* __restrict__ l2,
                                                        float* __restrict__ g) {
  int idx = blockIdx.x * 256 + threadIdx.x;  // B*D = 4096
  int d = idx & (D_ - 1);
  int b = idx >> 10;
  const float b64 = 0.0011790184577739f;  // 0.9^64
  float G = 0.f;
  for (int ch = 0; ch < NCH; ++ch) {
    g[(size_t)(b * NCH + ch) * D_ + d] = G;
    float lf = l2[(size_t)(b * T_ + ch * ECH + ECH - 1) * D_ + d];
    G = lf + b64 * G;
  }
}

// fix + convert to bf16 (l2 f32 is dead after this kernel)
__global__ __launch_bounds__(256) void ema_fix_kernel(const float* __restrict__ l2,
                                                      const float* __restrict__ g,
                                                      short* __restrict__ l2b) {
  int idx = blockIdx.x * 256 + threadIdx.x;  // 4M
  int d = idx & (D_ - 1);
  int t = (idx >> 10) & (T_ - 1);
  int b = idx >> 20;
  int ch = t >> 6;
  int off = t & (ECH - 1);
  float G = g[(size_t)(b * NCH + ch) * D_ + d];
  l2b[idx] = f2b(l2[idx] + powf(0.9f, (float)(off + 1)) * G);
}

// ---------------- f32 -> bf16 convert (vectorized) ----------------
__global__ __launch_bounds__(256) void cvt_bf16_kernel(const float* __restrict__ in,
                                                       short* __restrict__ out) {
  int idx = blockIdx.x * 256 + threadIdx.x;
  float4 v = ((const float4*)in)[idx];
  s16x4 o;
  o[0] = f2b(v.x); o[1] = f2b(v.y); o[2] = f2b(v.z); o[3] = f2b(v.w);
  ((s16x4*)out)[idx] = o;
}

// ---------------- weight transpose + convert: Wt[n][k] = bf16(W[k][n]) ----------------
__global__ __launch_bounds__(256) void transpose_w_kernel(
    const float* __restrict__ w0, const float* __restrict__ w1,
    const float* __restrict__ w2, const float* __restrict__ w3,
    const float* __restrict__ w4,
    short* __restrict__ t0, short* __restrict__ t1, short* __restrict__ t2,
    short* __restrict__ t3, short* __restrict__ t4) {
  int z = blockIdx.z;
  const float* W = (z == 0) ? w0 : (z == 1) ? w1 : (z == 2) ? w2 : (z == 3) ? w3 : w4;
  short* Wt = (z == 0) ? t0 : (z == 1) ? t1 : (z == 2) ? t2 : (z == 3) ? t3 : t4;
  int cols = (z == 4) ? 512 : 1024;
  int c0 = blockIdx.x * 32, r0 = blockIdx.y * 32;
  if (c0 >= cols) return;
  __shared__ float tile[32][33];
  int tc = threadIdx.x & 31, tr8 = threadIdx.x >> 5;
#pragma unroll
  for (int i = 0; i < 4; ++i)
    tile[tr8 + i * 8][tc] = W[(size_t)(r0 + tr8 + i * 8) * cols + c0 + tc];
  __syncthreads();
#pragma unroll
  for (int i = 0; i < 4; ++i) {
    int rr = tr8 + i * 8;
    Wt[(size_t)(c0 + rr) * 1024 + r0 + tc] = f2b(tile[tc][rr]);
  }
}

// ---------------- bf16 MFMA GEMM: C[M,N] = A[M,K] @ Bt[N,K]^T ----------------
// 128x128 tile, BK=64, 4 waves (2x2), global_load_lds 16B, XOR(row&7) k8-swizzle.
__global__ __launch_bounds__(256) void gemm_bt(const short* __restrict__ A,
                                               const short* __restrict__ Bt,
                                               float* __restrict__ Cf,
                                               short* __restrict__ Cb,
                                               int Ndim, int Kdim) {
  __shared__ short As[128 * 64];
  __shared__ short Bs[128 * 64];
  int tid = threadIdx.x;
  int w = tid >> 6, l = tid & 63;
  int lg = l >> 4, ll = l & 15;
  int wr = w >> 1, wc = w & 1;
  int row0 = blockIdx.y * 128, col0 = blockIdx.x * 128;

  f32x4 acc[4][4];
#pragma unroll
  for (int m = 0; m < 4; ++m)
#pragma unroll
    for (int n = 0; n < 4; ++n) acc[m][n] = (f32x4){0.f, 0.f, 0.f, 0.f};

  for (int k0 = 0; k0 < Kdim; k0 += 64) {
    __syncthreads();
#pragma unroll
    for (int it = 0; it < 4; ++it) {
      int s = it * 256 + w * 64 + l;
      int r = s >> 3;
      int c = (s & 7) ^ (r & 7);  // pre-swizzled source (linear LDS dest)
      gload_lds16(A + (size_t)(row0 + r) * Kdim + k0 + c * 8, &As[(it * 256 + w * 64) * 8]);
      gload_lds16(Bt + (size_t)(col0 + r) * Kdim + k0 + c * 8, &Bs[(it * 256 + w * 64) * 8]);
    }
    __syncthreads();
#pragma unroll
    for (int ks = 0; ks < 2; ++ks) {
      bf16x8 af[4], bfr[4];
#pragma unroll
      for (int m = 0; m < 4; ++m) {
        int r = wr * 64 + m * 16 + ll;
        af[m] = *(const bf16x8*)&As[r * 64 + (((ks * 4 + lg) ^ (r & 7)) << 3)];
      }
#pragma unroll
      for (int n = 0; n < 4; ++n) {
        int r = wc * 64 + n * 16 + ll;
        bfr[n] = *(const bf16x8*)&Bs[r * 64 + (((ks * 4 + lg) ^ (r & 7)) << 3)];
      }
#pragma unroll
      for (int m = 0; m < 4; ++m)
#pragma unroll
        for (int n = 0; n < 4; ++n)
          acc[m][n] = __builtin_amdgcn_mfma_f32_16x16x32_bf16(af[m], bfr[n], acc[m][n], 0, 0, 0);
    }
  }
#pragma unroll
  for (int m = 0; m < 4; ++m) {
    int gr = row0 + wr * 64 + m * 16 + lg * 4;
#pragma unroll
    for (int n = 0; n < 4; ++n) {
      int gc = col0 + wc * 64 + n * 16 + ll;
#pragma unroll
      for (int r = 0; r < 4; ++r) {
        float vv = acc[m][n][r];
        if (Cf) Cf[(size_t)(gr + r) * Ndim + gc] = vv;
        if (Cb) Cb[(size_t)(gr + r) * Ndim + gc] = f2b(vv);
      }
    }
  }
}

// ---------------- v3 = l3_memory @ wv  ([B,1024], f32) ----------------
__global__ __launch_bounds__(256) void v3_kernel(const float* __restrict__ l3,
                                                 const float* __restrict__ wv,
                                                 float* __restrict__ v3) {
  int idx = blockIdx.x * 256 + threadIdx.x;  // B*D = 4096
  int b = idx >> 10;
  int col = idx & 1023;
  const float* xr = l3 + (size_t)b * D_;
  float acc = 0.f;
#pragma unroll 8
  for (int k = 0; k < D_; ++k) acc += xr[k] * wv[(size_t)k * D_ + col];
  v3[idx] = acc;
}

// ---------------- router ----------------
__global__ __launch_bounds__(256) void router_kernel(const float* __restrict__ hdnp,
                                                     const float* __restrict__ rb1,
                                                     const float* __restrict__ rw2,
                                                     const float* __restrict__ rb2,
                                                     float* __restrict__ lam) {
  int wave = (blockIdx.x * 256 + threadIdx.x) >> 6;
  int lane = threadIdx.x & 63;
  const float* hr = hdnp + (size_t)wave * 512;
  float s0 = 0.f, s1 = 0.f, s2 = 0.f;
#pragma unroll
  for (int u = 0; u < 8; ++u) {
    int hcol = u * 64 + lane;
    float vv = hr[hcol] + rb1[hcol];
    float gl = 0.5f * vv * (1.0f + erff(vv * 0.70710678118654752f));
    s0 += gl * rw2[hcol * 3 + 0];
    s1 += gl * rw2[hcol * 3 + 1];
    s2 += gl * rw2[hcol * 3 + 2];
  }
#pragma unroll
  for (int off = 32; off; off >>= 1) {
    s0 += __shfl_xor(s0, off);
    s1 += __shfl_xor(s1, off);
    s2 += __shfl_xor(s2, off);
  }
  if (lane == 0) {
    float a = s0 + rb2[0], bb = s1 + rb2[1], c = s2 + rb2[2];
    float m = fmaxf(fmaxf(a, bb), c);
    float e0 = expf(a - m), e1 = expf(bb - m), e2 = expf(c - m);
    float inv = 1.0f / (e0 + e1 + e2);
    lam[(size_t)wave * 3 + 0] = e0 * inv;
    lam[(size_t)wave * 3 + 1] = e1 * inv;
    lam[(size_t)wave * 3 + 2] = e2 * inv;
  }
}

// ---------------- mixed init ([b,t,d]): lam[...,2] * broadcast(v3) ----------------
__global__ __launch_bounds__(256) void init_mixed_kernel(const float* __restrict__ lam,
                                                         const float* __restrict__ v3,
                                                         float* __restrict__ mixed) {
  int idx = blockIdx.x * 256 + threadIdx.x;  // 4M
  int d = idx & 1023;
  int t = (idx >> 10) & 1023;
  int b = idx >> 20;
  mixed[idx] = lam[(size_t)(b * T_ + t) * 3 + 2] * v3[(b << 10) + d];
}

// ---------------- MFMA flash attention (bf16 inputs), accumulate into mixed[b,t,d] ----------------
__global__ __launch_bounds__(256) void attn_mfma_kernel(const short* __restrict__ q,
                                                        const short* __restrict__ k,
                                                        const short* __restrict__ v,
                                                        const float* __restrict__ lam, int lamcol,
                                                        float* __restrict__ mixed) {
  __shared__ short Qs[64][72];      // [qrow][dh], 144B stride (16B-aligned)
  __shared__ short Ks[32][72];      // [key][dh]
  __shared__ short Vt[64][40];      // [dh][key], 80B stride
  __shared__ short Ps[4][16][40];   // per-wave P tile [qrow][key]

  int bh = blockIdx.y;
  int b = bh >> 4, h = bh & 15;
  int q0 = blockIdx.x * 64;
  int tid = threadIdx.x;
  int w = tid >> 6, l = tid & 63;
  int lg = l >> 4;
  int ll = l & 15;

  // stage Q tile (vectorized 16B)
#pragma unroll
  for (int it = 0; it < 2; ++it) {
    int e = it * 256 + tid;
    int r = e >> 3, c8 = e & 7;
    *(bf16x8*)&Qs[r][c8 * 8] =
        *(const bf16x8*)&q[(size_t)(b * T_ + q0 + r) * D_ + h * DH_ + c8 * 8];
  }
  __syncthreads();

  bf16x8 qf0 = *(const bf16x8*)&Qs[w * 16 + ll][lg * 8];
  bf16x8 qf1 = *(const bf16x8*)&Qs[w * 16 + ll][32 + lg * 8];

  float m_[4], l_[4];
  f32x4 o[4];
#pragma unroll
  for (int r = 0; r < 4; ++r) { m_[r] = -1e30f; l_[r] = 0.f; }
#pragma unroll
  for (int db = 0; db < 4; ++db) o[db] = (f32x4){0.f, 0.f, 0.f, 0.f};

  int qw0 = q0 + w * 16;
  int nt = (q0 + 64) >> 5;
  for (int kt = 0; kt < nt; ++kt) {
    __syncthreads();
    int key0 = kt * 32;
    {
      int r = tid >> 3, c8 = tid & 7;  // 256 = 32 rows x 8
      size_t gi = (size_t)(b * T_ + key0 + r) * D_ + h * DH_ + c8 * 8;
      *(bf16x8*)&Ks[r][c8 * 8] = *(const bf16x8*)&k[gi];
      bf16x8 vv = *(const bf16x8*)&v[gi];
#pragma unroll
      for (int j = 0; j < 8; ++j) Vt[c8 * 8 + j][r] = vv[j];
    }
    __syncthreads();
    if (key0 > qw0 + 15) continue;  // wave fully masked (uniform per wave)

    // ---- QK^T ----
    f32x4 c0 = (f32x4){0.f, 0.f, 0.f, 0.f}, c1 = (f32x4){0.f, 0.f, 0.f, 0.f};
    {
      bf16x8 kf0a = *(const bf16x8*)&Ks[ll][lg * 8];
      bf16x8 kf0b = *(const bf16x8*)&Ks[ll][32 + lg * 8];
      bf16x8 kf1a = *(const bf16x8*)&Ks[16 + ll][lg * 8];
      bf16x8 kf1b = *(const bf16x8*)&Ks[16 + ll][32 + lg * 8];
      c0 = __builtin_amdgcn_mfma_f32_16x16x32_bf16(qf0, kf0a, c0, 0, 0, 0);
      c0 = __builtin_amdgcn_mfma_f32_16x16x32_bf16(qf1, kf0b, c0, 0, 0, 0);
      c1 = __builtin_amdgcn_mfma_f32_16x16x32_bf16(qf0, kf1a, c1, 0, 0, 0);
      c1 = __builtin_amdgcn_mfma_f32_16x16x32_bf16(qf1, kf1b, c1, 0, 0, 0);
    }

    // ---- online softmax ----
    float al[4];
#pragma unroll
    for (int r = 0; r < 4; ++r) {
      int row = qw0 + lg * 4 + r;
      float s0 = c0[r] * 0.125f, s1 = c1[r] * 0.125f;
      if (key0 + ll > row) s0 = -1e30f;
      if (key0 + 16 + ll > row) s1 = -1e30f;
      float mx = fmaxf(s0, s1);
      mx = fmaxf(mx, __shfl_xor(mx, 1));
      mx = fmaxf(mx, __shfl_xor(mx, 2));
      mx = fmaxf(mx, __shfl_xor(mx, 4));
      mx = fmaxf(mx, __shfl_xor(mx, 8));
      float nm = fmaxf(m_[r], mx);
      al[r] = expf(m_[r] - nm);
      float p0 = expf(s0 - nm);
      float p1 = expf(s1 - nm);
      float rs = p0 + p1;
      rs += __shfl_xor(rs, 1);
      rs += __shfl_xor(rs, 2);
      rs += __shfl_xor(rs, 4);
      rs += __shfl_xor(rs, 8);
      l_[r] = l_[r] * al[r] + rs;
      m_[r] = nm;
      Ps[w][lg * 4 + r][ll] = f2b(p0);
      Ps[w][lg * 4 + r][16 + ll] = f2b(p1);
    }
#pragma unroll
    for (int db = 0; db < 4; ++db)
#pragma unroll
      for (int r = 0; r < 4; ++r) o[db][r] *= al[r];

    asm volatile("s_waitcnt lgkmcnt(0)" ::: "memory");

    // ---- PV ----
    bf16x8 pf = *(const bf16x8*)&Ps[w][ll][lg * 8];
#pragma unroll
    for (int db = 0; db < 4; ++db) {
      bf16x8 vf = *(const bf16x8*)&Vt[db * 16 + ll][lg * 8];
      o[db] = __builtin_amdgcn_mfma_f32_16x16x32_bf16(pf, vf, o[db], 0, 0, 0);
    }
  }

  // ---- epilogue ----
#pragma unroll
  for (int r = 0; r < 4; ++r) {
    int row = qw0 + lg * 4 + r;
    float lamv = lam[(size_t)(b * T_ + row) * 3 + lamcol] / l_[r];
#pragma unroll
    for (int db = 0; db < 4; ++db) {
      size_t oi = (size_t)(b * T_ + row) * D_ + h * DH_ + db * 16 + ll;
      mixed[oi] += lamv * o[db][r];
    }
  }
}

extern "C" void kernel_launch(void* const* d_in, const int* in_sizes, int n_in,
                              void* d_out, int out_size, void* d_ws, size_t ws_size,
                              hipStream_t stream) {
  const float* x = (const float*)d_in[0];
  const float* l3m = (const float*)d_in[1];
  const float* wq = (const float*)d_in[2];
  const float* wk = (const float*)d_in[3];
  const float* wv = (const float*)d_in[4];
  const float* wo = (const float*)d_in[5];
  const float* rw1 = (const float*)d_in[6];
  const float* rb1 = (const float*)d_in[7];
  const float* rw2 = (const float*)d_in[8];
  const float* rb2 = (const float*)d_in[9];

  float* out = (float*)d_out;
  float* lam = out + (size_t)M_ * D_;  // output tail: [4096,3]

  float* ws = (float*)d_ws;
  float* l2 = ws;                       // 4M floats (dead after ema_fix)
  float* mixed = ws;                    // alias of l2 (init_mixed runs after ema_fix)
  float* hdnp = ws + 4194304;           // 2M floats
  float* v3 = ws + 6291456;             // 4096
  float* gbuf = ws + 6295552;           // 65536
  short* sb = (short*)(ws + 6361088);
  short* xb = sb;                       // 4M shorts each
  short* l2b = sb + 4194304;
  short* qb = sb + 8388608;
  short* kb = sb + 12582912;
  short* vb = sb + 16777216;
  short* mixedb = sb + 20971520;
  short* wqT = sb + 25165824;           // 1M shorts each
  short* wkT = sb + 26214400;
  short* wvT = sb + 27262976;
  short* woT = sb + 28311552;
  short* rw1T = sb + 29360128;          // 512K shorts

  dim3 blk(256);
  dim3 gg(8, 32);    // N=1024 GEMM
  dim3 ggr(4, 32);   // N=512 GEMM
  dim3 attn_grid(16, 64);

  // weight transpose+convert, x convert (independent)
  transpose_w_kernel<<<dim3(32, 32, 5), blk, 0, stream>>>(wq, wk, wv, wo, rw1,
                                                          wqT, wkT, wvT, woT, rw1T);
  cvt_bf16_kernel<<<4096, blk, 0, stream>>>(x, xb);

  // EMA l2 -> l2b (bf16)
  ema_chunk_kernel<<<256, blk, 0, stream>>>(x, l2);
  ema_carry_kernel<<<16, blk, 0, stream>>>(l2, gbuf);
  ema_fix_kernel<<<16384, blk, 0, stream>>>(l2, gbuf, l2b);

  // q (bf16 only), router
  gemm_bt<<<gg, blk, 0, stream>>>(xb, wqT, (float*)nullptr, qb, 1024, 1024);
  gemm_bt<<<ggr, blk, 0, stream>>>(qb, rw1T, hdnp, (short*)nullptr, 512, 1024);
  router_kernel<<<1024, blk, 0, stream>>>(hdnp, rb1, rw2, rb2, lam);

  // l3 value vector + mixed init (mixed aliases l2: ema_fix already done)
  v3_kernel<<<16, blk, 0, stream>>>(l3m, wv, v3);
  init_mixed_kernel<<<16384, blk, 0, stream>>>(lam, v3, mixed);

  // pass 0: mem = x
  gemm_bt<<<gg, blk, 0, stream>>>(xb, wkT, (float*)nullptr, kb, 1024, 1024);
  gemm_bt<<<gg, blk, 0, stream>>>(xb, wvT, (float*)nullptr, vb, 1024, 1024);
  attn_mfma_kernel<<<attn_grid, blk, 0, stream>>>(qb, kb, vb, lam, 0, mixed);

  // pass 1: mem = l2
  gemm_bt<<<gg, blk, 0, stream>>>(l2b, wkT, (float*)nullptr, kb, 1024, 1024);
  gemm_bt<<<gg, blk, 0, stream>>>(l2b, wvT, (float*)nullptr, vb, 1024, 1024);
  attn_mfma_kernel<<<attn_grid, blk, 0, stream>>>(qb, kb, vb, lam, 1, mixed);

  // out = mixed @ wo
  cvt_bf16_kernel<<<4096, blk, 0, stream>>>(mixed, mixedb);
  gemm_bt<<<gg, blk, 0, stream>>>(mixedb, woT, out, (short*)nullptr, 1024, 1024);
}

// Round 4
// 414.690 us; speedup vs baseline: 5.3471x; 1.2615x over previous
//
#include <hip/hip_runtime.h>
#include <hip/hip_bf16.h>
#include <math.h>

// MKAFullAttention: B=4, T=1024, D=1024, H=16, DH=64, BETA=0.9
// Round 4: attention v2 — QBLK=128/KVBLK=64, conflict-free swizzled V-transpose
//          and P staging, exp2-domain online softmax. GEMMs unchanged (m97-style).
//   - l3 stream analytic: attend(l3) = broadcast(l3@wv).

#define B_ 4
#define T_ 1024
#define D_ 1024
#define H_ 16
#define DH_ 64
#define M_ 4096

#define ECH 64
#define NCH 16

typedef __attribute__((ext_vector_type(8))) short bf16x8;
typedef __attribute__((ext_vector_type(4))) short s16x4;
typedef __attribute__((ext_vector_type(4))) float f32x4;

__device__ inline short f2b(float f) {
  __hip_bfloat16 h = __float2bfloat16(f);
  return *reinterpret_cast<short*>(&h);
}

__device__ inline void gload_lds16(const short* g, short* l) {
  __builtin_amdgcn_global_load_lds(
      (const __attribute__((address_space(1))) unsigned int*)g,
      (__attribute__((address_space(3))) unsigned int*)l, 16, 0, 0);
}

// ---------------- EMA chunked scan ----------------
__global__ __launch_bounds__(256) void ema_chunk_kernel(const float* __restrict__ x,
                                                        float* __restrict__ l2) {
  int idx = blockIdx.x * 256 + threadIdx.x;  // B*NCH*D = 65536
  int d = idx & (D_ - 1);
  int ch = (idx >> 10) & (NCH - 1);
  int b = idx >> 14;
  const float* xp = x + (size_t)(b * T_ + ch * ECH) * D_ + d;
  float* yp = l2 + (size_t)(b * T_ + ch * ECH) * D_ + d;
  float y = 0.f;
#pragma unroll 4
  for (int t = 0; t < ECH; ++t) {
    y = 0.9f * y + 0.1f * xp[t * D_];
    yp[t * D_] = y;
  }
}

__global__ __launch_bounds__(256) void ema_carry_kernel(const float* __restrict__ l2,
                                                        float* __restrict__ g) {
  int idx = blockIdx.x * 256 + threadIdx.x;  // B*D = 4096
  int d = idx & (D_ - 1);
  int b = idx >> 10;
  const float b64 = 0.0011790184577739f;  // 0.9^64
  float G = 0.f;
  for (int ch = 0; ch < NCH; ++ch) {
    g[(size_t)(b * NCH + ch) * D_ + d] = G;
    float lf = l2[(size_t)(b * T_ + ch * ECH + ECH - 1) * D_ + d];
    G = lf + b64 * G;
  }
}

// fix + convert to bf16 (l2 f32 is dead after this kernel)
__global__ __launch_bounds__(256) void ema_fix_kernel(const float* __restrict__ l2,
                                                      const float* __restrict__ g,
                                                      short* __restrict__ l2b) {
  int idx = blockIdx.x * 256 + threadIdx.x;  // 4M
  int d = idx & (D_ - 1);
  int t = (idx >> 10) & (T_ - 1);
  int b = idx >> 20;
  int ch = t >> 6;
  int off = t & (ECH - 1);
  float G = g[(size_t)(b * NCH + ch) * D_ + d];
  l2b[idx] = f2b(l2[idx] + powf(0.9f, (float)(off + 1)) * G);
}

// ---------------- f32 -> bf16 convert (vectorized) ----------------
__global__ __launch_bounds__(256) void cvt_bf16_kernel(const float* __restrict__ in,
                                                       short* __restrict__ out) {
  int idx = blockIdx.x * 256 + threadIdx.x;
  float4 v = ((const float4*)in)[idx];
  s16x4 o;
  o[0] = f2b(v.x); o[1] = f2b(v.y); o[2] = f2b(v.z); o[3] = f2b(v.w);
  ((s16x4*)out)[idx] = o;
}

// ---------------- weight transpose + convert: Wt[n][k] = bf16(W[k][n]) ----------------
__global__ __launch_bounds__(256) void transpose_w_kernel(
    const float* __restrict__ w0, const float* __restrict__ w1,
    const float* __restrict__ w2, const float* __restrict__ w3,
    const float* __restrict__ w4,
    short* __restrict__ t0, short* __restrict__ t1, short* __restrict__ t2,
    short* __restrict__ t3, short* __restrict__ t4) {
  int z = blockIdx.z;
  const float* W = (z == 0) ? w0 : (z == 1) ? w1 : (z == 2) ? w2 : (z == 3) ? w3 : w4;
  short* Wt = (z == 0) ? t0 : (z == 1) ? t1 : (z == 2) ? t2 : (z == 3) ? t3 : t4;
  int cols = (z == 4) ? 512 : 1024;
  int c0 = blockIdx.x * 32, r0 = blockIdx.y * 32;
  if (c0 >= cols) return;
  __shared__ float tile[32][33];
  int tc = threadIdx.x & 31, tr8 = threadIdx.x >> 5;
#pragma unroll
  for (int i = 0; i < 4; ++i)
    tile[tr8 + i * 8][tc] = W[(size_t)(r0 + tr8 + i * 8) * cols + c0 + tc];
  __syncthreads();
#pragma unroll
  for (int i = 0; i < 4; ++i) {
    int rr = tr8 + i * 8;
    Wt[(size_t)(c0 + rr) * 1024 + r0 + tc] = f2b(tile[tc][rr]);
  }
}

// ---------------- bf16 MFMA GEMM: C[M,N] = A[M,K] @ Bt[N,K]^T ----------------
__global__ __launch_bounds__(256) void gemm_bt(const short* __restrict__ A,
                                               const short* __restrict__ Bt,
                                               float* __restrict__ Cf,
                                               short* __restrict__ Cb,
                                               int Ndim, int Kdim) {
  __shared__ short As[128 * 64];
  __shared__ short Bs[128 * 64];
  int tid = threadIdx.x;
  int w = tid >> 6, l = tid & 63;
  int lg = l >> 4, ll = l & 15;
  int wr = w >> 1, wc = w & 1;
  int row0 = blockIdx.y * 128, col0 = blockIdx.x * 128;

  f32x4 acc[4][4];
#pragma unroll
  for (int m = 0; m < 4; ++m)
#pragma unroll
    for (int n = 0; n < 4; ++n) acc[m][n] = (f32x4){0.f, 0.f, 0.f, 0.f};

  for (int k0 = 0; k0 < Kdim; k0 += 64) {
    __syncthreads();
#pragma unroll
    for (int it = 0; it < 4; ++it) {
      int s = it * 256 + w * 64 + l;
      int r = s >> 3;
      int c = (s & 7) ^ (r & 7);  // pre-swizzled source (linear LDS dest)
      gload_lds16(A + (size_t)(row0 + r) * Kdim + k0 + c * 8, &As[(it * 256 + w * 64) * 8]);
      gload_lds16(Bt + (size_t)(col0 + r) * Kdim + k0 + c * 8, &Bs[(it * 256 + w * 64) * 8]);
    }
    __syncthreads();
#pragma unroll
    for (int ks = 0; ks < 2; ++ks) {
      bf16x8 af[4], bfr[4];
#pragma unroll
      for (int m = 0; m < 4; ++m) {
        int r = wr * 64 + m * 16 + ll;
        af[m] = *(const bf16x8*)&As[r * 64 + (((ks * 4 + lg) ^ (r & 7)) << 3)];
      }
#pragma unroll
      for (int n = 0; n < 4; ++n) {
        int r = wc * 64 + n * 16 + ll;
        bfr[n] = *(const bf16x8*)&Bs[r * 64 + (((ks * 4 + lg) ^ (r & 7)) << 3)];
      }
#pragma unroll
      for (int m = 0; m < 4; ++m)
#pragma unroll
        for (int n = 0; n < 4; ++n)
          acc[m][n] = __builtin_amdgcn_mfma_f32_16x16x32_bf16(af[m], bfr[n], acc[m][n], 0, 0, 0);
    }
  }
#pragma unroll
  for (int m = 0; m < 4; ++m) {
    int gr = row0 + wr * 64 + m * 16 + lg * 4;
#pragma unroll
    for (int n = 0; n < 4; ++n) {
      int gc = col0 + wc * 64 + n * 16 + ll;
#pragma unroll
      for (int r = 0; r < 4; ++r) {
        float vv = acc[m][n][r];
        if (Cf) Cf[(size_t)(gr + r) * Ndim + gc] = vv;
        if (Cb) Cb[(size_t)(gr + r) * Ndim + gc] = f2b(vv);
      }
    }
  }
}

// ---------------- v3 = l3_memory @ wv  ([B,1024], f32) ----------------
__global__ __launch_bounds__(256) void v3_kernel(const float* __restrict__ l3,
                                                 const float* __restrict__ wv,
                                                 float* __restrict__ v3) {
  int idx = blockIdx.x * 256 + threadIdx.x;  // B*D = 4096
  int b = idx >> 10;
  int col = idx & 1023;
  const float* xr = l3 + (size_t)b * D_;
  float acc = 0.f;
#pragma unroll 8
  for (int k = 0; k < D_; ++k) acc += xr[k] * wv[(size_t)k * D_ + col];
  v3[idx] = acc;
}

// ---------------- router ----------------
__global__ __launch_bounds__(256) void router_kernel(const float* __restrict__ hdnp,
                                                     const float* __restrict__ rb1,
                                                     const float* __restrict__ rw2,
                                                     const float* __restrict__ rb2,
                                                     float* __restrict__ lam) {
  int wave = (blockIdx.x * 256 + threadIdx.x) >> 6;
  int lane = threadIdx.x & 63;
  const float* hr = hdnp + (size_t)wave * 512;
  float s0 = 0.f, s1 = 0.f, s2 = 0.f;
#pragma unroll
  for (int u = 0; u < 8; ++u) {
    int hcol = u * 64 + lane;
    float vv = hr[hcol] + rb1[hcol];
    float gl = 0.5f * vv * (1.0f + erff(vv * 0.70710678118654752f));
    s0 += gl * rw2[hcol * 3 + 0];
    s1 += gl * rw2[hcol * 3 + 1];
    s2 += gl * rw2[hcol * 3 + 2];
  }
#pragma unroll
  for (int off = 32; off; off >>= 1) {
    s0 += __shfl_xor(s0, off);
    s1 += __shfl_xor(s1, off);
    s2 += __shfl_xor(s2, off);
  }
  if (lane == 0) {
    float a = s0 + rb2[0], bb = s1 + rb2[1], c = s2 + rb2[2];
    float m = fmaxf(fmaxf(a, bb), c);
    float e0 = expf(a - m), e1 = expf(bb - m), e2 = expf(c - m);
    float inv = 1.0f / (e0 + e1 + e2);
    lam[(size_t)wave * 3 + 0] = e0 * inv;
    lam[(size_t)wave * 3 + 1] = e1 * inv;
    lam[(size_t)wave * 3 + 2] = e2 * inv;
  }
}

// ---------------- mixed init ([b,t,d]): lam[...,2] * broadcast(v3) ----------------
__global__ __launch_bounds__(256) void init_mixed_kernel(const float* __restrict__ lam,
                                                         const float* __restrict__ v3,
                                                         float* __restrict__ mixed) {
  int idx = blockIdx.x * 256 + threadIdx.x;  // 4M
  int d = idx & 1023;
  int t = (idx >> 10) & 1023;
  int b = idx >> 20;
  mixed[idx] = lam[(size_t)(b * T_ + t) * 3 + 2] * v3[(b << 10) + d];
}

// ---------------- MFMA flash attention v2 ----------------
// Block: 128 q-rows of one (b,h); 4 waves x 32 rows (2 x 16-row frags). KV tile 64.
// Vt: [dh][key] dword-packed pairs, XOR-swizzled (conflict-free write+read).
// Ps: per-wave [32 rows][64 keys], kt XOR-swizzled.
__global__ __launch_bounds__(256) void attn_mfma_kernel(const short* __restrict__ q,
                                                        const short* __restrict__ k,
                                                        const short* __restrict__ v,
                                                        const float* __restrict__ lam, int lamcol,
                                                        float* __restrict__ mixed) {
  __shared__ short Qs[128][72];
  __shared__ short Ks[64][72];
  __shared__ short Vt[64][64];      // [dh][key], dword-swizzled
  __shared__ short Ps[4][32][64];   // per-wave P, kt-swizzled

  int bh = blockIdx.y;
  int b = bh >> 4, h = bh & 15;
  int q0 = blockIdx.x * 128;
  int tid = threadIdx.x;
  int w = tid >> 6, l = tid & 63;
  int lg = l >> 4, ll = l & 15;

  // stage Q (128 x 64), 16B vector copies
#pragma unroll
  for (int it = 0; it < 4; ++it) {
    int e = it * 256 + tid;
    int r = e >> 3, c8 = e & 7;
    *(bf16x8*)&Qs[r][c8 * 8] =
        *(const bf16x8*)&q[(size_t)(b * T_ + q0 + r) * D_ + h * DH_ + c8 * 8];
  }
  __syncthreads();

  int qw0 = q0 + w * 32;
  bf16x8 qf[2][2];
#pragma unroll
  for (int rf = 0; rf < 2; ++rf) {
    qf[rf][0] = *(const bf16x8*)&Qs[w * 32 + rf * 16 + ll][lg * 8];
    qf[rf][1] = *(const bf16x8*)&Qs[w * 32 + rf * 16 + ll][32 + lg * 8];
  }

  float m_[2][4], l_[2][4];
  f32x4 o[2][4];
#pragma unroll
  for (int rf = 0; rf < 2; ++rf)
#pragma unroll
    for (int r = 0; r < 4; ++r) { m_[rf][r] = -1e30f; l_[rf][r] = 0.f; }
#pragma unroll
  for (int rf = 0; rf < 2; ++rf)
#pragma unroll
    for (int db = 0; db < 4; ++db) o[rf][db] = (f32x4){0.f, 0.f, 0.f, 0.f};

  const float SC = 0.125f * 1.44269504f;  // scale * log2(e): softmax in exp2 domain
  int nt = (q0 >> 6) + 2;
  for (int t64 = 0; t64 < nt; ++t64) {
    int key0 = t64 * 64;
    __syncthreads();
    // stage K (64 x 64), 16B copies
#pragma unroll
    for (int it = 0; it < 2; ++it) {
      int e = it * 256 + tid;
      int r = e >> 3, c8 = e & 7;
      *(bf16x8*)&Ks[r][c8 * 8] =
          *(const bf16x8*)&k[(size_t)(b * T_ + key0 + r) * D_ + h * DH_ + c8 * 8];
    }
    // stage V transposed: key-pair dwords, swizzle dw ^= ((dh^(dh>>3))&7)<<2
    {
      int kp = tid >> 3, c8 = tid & 7;
      size_t gi = (size_t)(b * T_ + key0 + kp * 2) * D_ + h * DH_ + c8 * 8;
      bf16x8 v0 = *(const bf16x8*)&v[gi];
      bf16x8 v1 = *(const bf16x8*)&v[gi + D_];
      unsigned int* Vtd = (unsigned int*)Vt;
#pragma unroll
      for (int j = 0; j < 8; ++j) {
        int dh = c8 * 8 + j;
        int X = ((dh ^ (dh >> 3)) & 7) << 2;
        Vtd[dh * 32 + (kp ^ X)] =
            ((unsigned int)(unsigned short)v0[j]) |
            (((unsigned int)(unsigned short)v1[j]) << 16);
      }
    }
    __syncthreads();
    if (key0 > qw0 + 31) continue;  // wave fully masked (uniform per wave)

    // ---- QK^T: 16 MFMA ----
    f32x4 c[2][4];
#pragma unroll
    for (int rf = 0; rf < 2; ++rf)
#pragma unroll
      for (int kt = 0; kt < 4; ++kt) c[rf][kt] = (f32x4){0.f, 0.f, 0.f, 0.f};
#pragma unroll
    for (int kt = 0; kt < 4; ++kt) {
      bf16x8 kfa = *(const bf16x8*)&Ks[kt * 16 + ll][lg * 8];
      bf16x8 kfb = *(const bf16x8*)&Ks[kt * 16 + ll][32 + lg * 8];
#pragma unroll
      for (int rf = 0; rf < 2; ++rf) {
        c[rf][kt] = __builtin_amdgcn_mfma_f32_16x16x32_bf16(qf[rf][0], kfa, c[rf][kt], 0, 0, 0);
        c[rf][kt] = __builtin_amdgcn_mfma_f32_16x16x32_bf16(qf[rf][1], kfb, c[rf][kt], 0, 0, 0);
      }
    }

    // ---- online softmax (exp2 domain) + P write ----
#pragma unroll
    for (int rf = 0; rf < 2; ++rf) {
#pragma unroll
      for (int r = 0; r < 4; ++r) {
        int grow = qw0 + rf * 16 + lg * 4 + r;
        float sv[4];
#pragma unroll
        for (int kt = 0; kt < 4; ++kt) {
          float s = c[rf][kt][r] * SC;
          sv[kt] = (key0 + kt * 16 + ll > grow) ? -1e30f : s;
        }
        float mx = fmaxf(fmaxf(sv[0], sv[1]), fmaxf(sv[2], sv[3]));
        mx = fmaxf(mx, __shfl_xor(mx, 1));
        mx = fmaxf(mx, __shfl_xor(mx, 2));
        mx = fmaxf(mx, __shfl_xor(mx, 4));
        mx = fmaxf(mx, __shfl_xor(mx, 8));
        float nm = fmaxf(m_[rf][r], mx);
        float al = exp2f(m_[rf][r] - nm);
        m_[rf][r] = nm;
        int prow = rf * 16 + lg * 4 + r;
        float rs = 0.f;
#pragma unroll
        for (int kt = 0; kt < 4; ++kt) {
          float p = exp2f(sv[kt] - nm);
          rs += p;
          Ps[w][prow][((kt ^ lg) << 4) + ll] = f2b(p);  // swizzle: kt ^ ((prow>>2)&3)=lg
        }
        rs += __shfl_xor(rs, 1);
        rs += __shfl_xor(rs, 2);
        rs += __shfl_xor(rs, 4);
        rs += __shfl_xor(rs, 8);
        l_[rf][r] = l_[rf][r] * al + rs;
#pragma unroll
        for (int db = 0; db < 4; ++db) o[rf][db][r] *= al;
      }
    }
    asm volatile("s_waitcnt lgkmcnt(0)" ::: "memory");
    __builtin_amdgcn_sched_barrier(0);

    // ---- PV: 16 MFMA ----
#pragma unroll
    for (int ks = 0; ks < 2; ++ks) {
      int pswz = (ks * 32 + lg * 8) ^ ((ll >> 2) << 4);
      bf16x8 pf0 = *(const bf16x8*)&Ps[w][ll][pswz];
      bf16x8 pf1 = *(const bf16x8*)&Ps[w][16 + ll][pswz];
      const unsigned int* Vtd = (const unsigned int*)Vt;
#pragma unroll
      for (int db = 0; db < 4; ++db) {
        int dh = db * 16 + ll;
        int X = ((dh ^ (dh >> 3)) & 7) << 2;
        bf16x8 vf = *(const bf16x8*)&Vtd[dh * 32 + ((ks * 16 + lg * 4) ^ X)];
        o[0][db] = __builtin_amdgcn_mfma_f32_16x16x32_bf16(pf0, vf, o[0][db], 0, 0, 0);
        o[1][db] = __builtin_amdgcn_mfma_f32_16x16x32_bf16(pf1, vf, o[1][db], 0, 0, 0);
      }
    }
  }

  // ---- epilogue: *lam/l, accumulate into mixed[b,t,d] ----
#pragma unroll
  for (int rf = 0; rf < 2; ++rf)
#pragma unroll
    for (int r = 0; r < 4; ++r) {
      int grow = qw0 + rf * 16 + lg * 4 + r;
      float lamv = lam[(size_t)(b * T_ + grow) * 3 + lamcol] / l_[rf][r];
#pragma unroll
      for (int db = 0; db < 4; ++db) {
        size_t oi = (size_t)(b * T_ + grow) * D_ + h * DH_ + db * 16 + ll;
        mixed[oi] += lamv * o[rf][db][r];
      }
    }
}

extern "C" void kernel_launch(void* const* d_in, const int* in_sizes, int n_in,
                              void* d_out, int out_size, void* d_ws, size_t ws_size,
                              hipStream_t stream) {
  const float* x = (const float*)d_in[0];
  const float* l3m = (const float*)d_in[1];
  const float* wq = (const float*)d_in[2];
  const float* wk = (const float*)d_in[3];
  const float* wv = (const float*)d_in[4];
  const float* wo = (const float*)d_in[5];
  const float* rw1 = (const float*)d_in[6];
  const float* rb1 = (const float*)d_in[7];
  const float* rw2 = (const float*)d_in[8];
  const float* rb2 = (const float*)d_in[9];

  float* out = (float*)d_out;
  float* lam = out + (size_t)M_ * D_;  // output tail: [4096,3]

  float* ws = (float*)d_ws;
  float* l2 = ws;                       // 4M floats (dead after ema_fix)
  float* mixed = ws;                    // alias of l2 (init_mixed runs after ema_fix)
  float* hdnp = ws + 4194304;           // 2M floats
  float* v3 = ws + 6291456;             // 4096
  float* gbuf = ws + 6295552;           // 65536
  short* sb = (short*)(ws + 6361088);
  short* xb = sb;                       // 4M shorts each
  short* l2b = sb + 4194304;
  short* qb = sb + 8388608;
  short* kb = sb + 12582912;
  short* vb = sb + 16777216;
  short* mixedb = sb + 20971520;
  short* wqT = sb + 25165824;           // 1M shorts each
  short* wkT = sb + 26214400;
  short* wvT = sb + 27262976;
  short* woT = sb + 28311552;
  short* rw1T = sb + 29360128;          // 512K shorts

  dim3 blk(256);
  dim3 gg(8, 32);    // N=1024 GEMM
  dim3 ggr(4, 32);   // N=512 GEMM
  dim3 attn_grid(8, 64);  // 8 q-blocks (128 rows) x (b,h)

  // weight transpose+convert, x convert (independent)
  transpose_w_kernel<<<dim3(32, 32, 5), blk, 0, stream>>>(wq, wk, wv, wo, rw1,
                                                          wqT, wkT, wvT, woT, rw1T);
  cvt_bf16_kernel<<<4096, blk, 0, stream>>>(x, xb);

  // EMA l2 -> l2b (bf16)
  ema_chunk_kernel<<<256, blk, 0, stream>>>(x, l2);
  ema_carry_kernel<<<16, blk, 0, stream>>>(l2, gbuf);
  ema_fix_kernel<<<16384, blk, 0, stream>>>(l2, gbuf, l2b);

  // q (bf16 only), router
  gemm_bt<<<gg, blk, 0, stream>>>(xb, wqT, (float*)nullptr, qb, 1024, 1024);
  gemm_bt<<<ggr, blk, 0, stream>>>(qb, rw1T, hdnp, (short*)nullptr, 512, 1024);
  router_kernel<<<1024, blk, 0, stream>>>(hdnp, rb1, rw2, rb2, lam);

  // l3 value vector + mixed init (mixed aliases l2: ema_fix already done)
  v3_kernel<<<16, blk, 0, stream>>>(l3m, wv, v3);
  init_mixed_kernel<<<16384, blk, 0, stream>>>(lam, v3, mixed);

  // pass 0: mem = x
  gemm_bt<<<gg, blk, 0, stream>>>(xb, wkT, (float*)nullptr, kb, 1024, 1024);
  gemm_bt<<<gg, blk, 0, stream>>>(xb, wvT, (float*)nullptr, vb, 1024, 1024);
  attn_mfma_kernel<<<attn_grid, blk, 0, stream>>>(qb, kb, vb, lam, 0, mixed);

  // pass 1: mem = l2
  gemm_bt<<<gg, blk, 0, stream>>>(l2b, wkT, (float*)nullptr, kb, 1024, 1024);
  gemm_bt<<<gg, blk, 0, stream>>>(l2b, wvT, (float*)nullptr, vb, 1024, 1024);
  attn_mfma_kernel<<<attn_grid, blk, 0, stream>>>(qb, kb, vb, lam, 1, mixed);

  // out = mixed @ wo
  cvt_bf16_kernel<<<4096, blk, 0, stream>>>(mixed, mixedb);
  gemm_bt<<<gg, blk, 0, stream>>>(mixedb, woT, out, (short*)nullptr, 1024, 1024);
}

// Round 5
// 334.256 us; speedup vs baseline: 6.6338x; 1.2406x over previous
//
#include <hip/hip_runtime.h>
#include <hip/hip_bf16.h>
#include <math.h>

// MKAFullAttention: B=4, T=1024, D=1024, H=16, DH=64, BETA=0.9
// Round 5: fused QKV/KV2 GEMMs (N=3072/2048), fused dual-stream attention
//          (both memory streams, direct-global Q frags, bf16 mixed output,
//          pair-sum causal load balancing), powf->exp2f in EMA fix.
//   - l3 stream analytic: attend(l3) = broadcast(l3@wv).

#define B_ 4
#define T_ 1024
#define D_ 1024
#define H_ 16
#define DH_ 64
#define M_ 4096

#define ECH 64
#define NCH 16

typedef __attribute__((ext_vector_type(8))) short bf16x8;
typedef __attribute__((ext_vector_type(4))) short s16x4;
typedef __attribute__((ext_vector_type(4))) float f32x4;

__device__ inline short f2b(float f) {
  __hip_bfloat16 h = __float2bfloat16(f);
  return *reinterpret_cast<short*>(&h);
}

__device__ inline void gload_lds16(const short* g, short* l) {
  __builtin_amdgcn_global_load_lds(
      (const __attribute__((address_space(1))) unsigned int*)g,
      (__attribute__((address_space(3))) unsigned int*)l, 16, 0, 0);
}

// ---------------- EMA chunked scan ----------------
__global__ __launch_bounds__(256) void ema_chunk_kernel(const float* __restrict__ x,
                                                        float* __restrict__ l2) {
  int idx = blockIdx.x * 256 + threadIdx.x;  // B*NCH*D = 65536
  int d = idx & (D_ - 1);
  int ch = (idx >> 10) & (NCH - 1);
  int b = idx >> 14;
  const float* xp = x + (size_t)(b * T_ + ch * ECH) * D_ + d;
  float* yp = l2 + (size_t)(b * T_ + ch * ECH) * D_ + d;
  float y = 0.f;
#pragma unroll 4
  for (int t = 0; t < ECH; ++t) {
    y = 0.9f * y + 0.1f * xp[t * D_];
    yp[t * D_] = y;
  }
}

__global__ __launch_bounds__(256) void ema_carry_kernel(const float* __restrict__ l2,
                                                        float* __restrict__ g) {
  int idx = blockIdx.x * 256 + threadIdx.x;  // B*D = 4096
  int d = idx & (D_ - 1);
  int b = idx >> 10;
  const float b64 = 0.0011790184577739f;  // 0.9^64
  float G = 0.f;
  for (int ch = 0; ch < NCH; ++ch) {
    g[(size_t)(b * NCH + ch) * D_ + d] = G;
    float lf = l2[(size_t)(b * T_ + ch * ECH + ECH - 1) * D_ + d];
    G = lf + b64 * G;
  }
}

// fix + convert to bf16 (l2 f32 is dead after this kernel)
__global__ __launch_bounds__(256) void ema_fix_kernel(const float* __restrict__ l2,
                                                      const float* __restrict__ g,
                                                      short* __restrict__ l2b) {
  int idx = blockIdx.x * 256 + threadIdx.x;  // 4M
  int d = idx & (D_ - 1);
  int t = (idx >> 10) & (T_ - 1);
  int b = idx >> 20;
  int ch = t >> 6;
  int off = t & (ECH - 1);
  float G = g[(size_t)(b * NCH + ch) * D_ + d];
  // 0.9^(off+1) = exp2((off+1)*log2(0.9))
  float p9 = exp2f((float)(off + 1) * -0.15200309344504997f);
  l2b[idx] = f2b(l2[idx] + p9 * G);
}

// ---------------- f32 -> bf16 convert (vectorized) ----------------
__global__ __launch_bounds__(256) void cvt_bf16_kernel(const float* __restrict__ in,
                                                       short* __restrict__ out) {
  int idx = blockIdx.x * 256 + threadIdx.x;
  float4 v = ((const float4*)in)[idx];
  s16x4 o;
  o[0] = f2b(v.x); o[1] = f2b(v.y); o[2] = f2b(v.z); o[3] = f2b(v.w);
  ((s16x4*)out)[idx] = o;
}

// ---------------- weight transpose + convert: Wt[n][k] = bf16(W[k][n]) ----------------
__global__ __launch_bounds__(256) void transpose_w_kernel(
    const float* __restrict__ w0, const float* __restrict__ w1,
    const float* __restrict__ w2, const float* __restrict__ w3,
    const float* __restrict__ w4,
    short* __restrict__ t0, short* __restrict__ t1, short* __restrict__ t2,
    short* __restrict__ t3, short* __restrict__ t4) {
  int z = blockIdx.z;
  const float* W = (z == 0) ? w0 : (z == 1) ? w1 : (z == 2) ? w2 : (z == 3) ? w3 : w4;
  short* Wt = (z == 0) ? t0 : (z == 1) ? t1 : (z == 2) ? t2 : (z == 3) ? t3 : t4;
  int cols = (z == 4) ? 512 : 1024;
  int c0 = blockIdx.x * 32, r0 = blockIdx.y * 32;
  if (c0 >= cols) return;
  __shared__ float tile[32][33];
  int tc = threadIdx.x & 31, tr8 = threadIdx.x >> 5;
#pragma unroll
  for (int i = 0; i < 4; ++i)
    tile[tr8 + i * 8][tc] = W[(size_t)(r0 + tr8 + i * 8) * cols + c0 + tc];
  __syncthreads();
#pragma unroll
  for (int i = 0; i < 4; ++i) {
    int rr = tr8 + i * 8;
    Wt[(size_t)(c0 + rr) * 1024 + r0 + tc] = f2b(tile[tc][rr]);
  }
}

// ---------------- bf16 MFMA GEMM: C[M,N] = A[M,K](lda) @ Bt[N,K]^T ----------------
// 128x128 tile, BK=64, 4 waves (2x2), global_load_lds 16B, XOR(row&7) k8-swizzle.
__global__ __launch_bounds__(256) void gemm_bt(const short* __restrict__ A, int lda,
                                               const short* __restrict__ Bt,
                                               float* __restrict__ Cf,
                                               short* __restrict__ Cb,
                                               int Ndim, int Kdim) {
  __shared__ short As[128 * 64];
  __shared__ short Bs[128 * 64];
  int tid = threadIdx.x;
  int w = tid >> 6, l = tid & 63;
  int lg = l >> 4, ll = l & 15;
  int wr = w >> 1, wc = w & 1;
  int row0 = blockIdx.y * 128, col0 = blockIdx.x * 128;

  f32x4 acc[4][4];
#pragma unroll
  for (int m = 0; m < 4; ++m)
#pragma unroll
    for (int n = 0; n < 4; ++n) acc[m][n] = (f32x4){0.f, 0.f, 0.f, 0.f};

  for (int k0 = 0; k0 < Kdim; k0 += 64) {
    __syncthreads();
#pragma unroll
    for (int it = 0; it < 4; ++it) {
      int s = it * 256 + w * 64 + l;
      int r = s >> 3;
      int c = (s & 7) ^ (r & 7);  // pre-swizzled source (linear LDS dest)
      gload_lds16(A + (size_t)(row0 + r) * lda + k0 + c * 8, &As[(it * 256 + w * 64) * 8]);
      gload_lds16(Bt + (size_t)(col0 + r) * Kdim + k0 + c * 8, &Bs[(it * 256 + w * 64) * 8]);
    }
    __syncthreads();
#pragma unroll
    for (int ks = 0; ks < 2; ++ks) {
      bf16x8 af[4], bfr[4];
#pragma unroll
      for (int m = 0; m < 4; ++m) {
        int r = wr * 64 + m * 16 + ll;
        af[m] = *(const bf16x8*)&As[r * 64 + (((ks * 4 + lg) ^ (r & 7)) << 3)];
      }
#pragma unroll
      for (int n = 0; n < 4; ++n) {
        int r = wc * 64 + n * 16 + ll;
        bfr[n] = *(const bf16x8*)&Bs[r * 64 + (((ks * 4 + lg) ^ (r & 7)) << 3)];
      }
#pragma unroll
      for (int m = 0; m < 4; ++m)
#pragma unroll
        for (int n = 0; n < 4; ++n)
          acc[m][n] = __builtin_amdgcn_mfma_f32_16x16x32_bf16(af[m], bfr[n], acc[m][n], 0, 0, 0);
    }
  }
#pragma unroll
  for (int m = 0; m < 4; ++m) {
    int gr = row0 + wr * 64 + m * 16 + lg * 4;
#pragma unroll
    for (int n = 0; n < 4; ++n) {
      int gc = col0 + wc * 64 + n * 16 + ll;
#pragma unroll
      for (int r = 0; r < 4; ++r) {
        float vv = acc[m][n][r];
        if (Cf) Cf[(size_t)(gr + r) * Ndim + gc] = vv;
        if (Cb) Cb[(size_t)(gr + r) * Ndim + gc] = f2b(vv);
      }
    }
  }
}

// ---------------- v3 = l3_memory @ wv  ([B,1024], f32) ----------------
__global__ __launch_bounds__(256) void v3_kernel(const float* __restrict__ l3,
                                                 const float* __restrict__ wv,
                                                 float* __restrict__ v3) {
  int idx = blockIdx.x * 256 + threadIdx.x;  // B*D = 4096
  int b = idx >> 10;
  int col = idx & 1023;
  const float* xr = l3 + (size_t)b * D_;
  float acc = 0.f;
#pragma unroll 8
  for (int k = 0; k < D_; ++k) acc += xr[k] * wv[(size_t)k * D_ + col];
  v3[idx] = acc;
}

// ---------------- router ----------------
__global__ __launch_bounds__(256) void router_kernel(const float* __restrict__ hdnp,
                                                     const float* __restrict__ rb1,
                                                     const float* __restrict__ rw2,
                                                     const float* __restrict__ rb2,
                                                     float* __restrict__ lam) {
  int wave = (blockIdx.x * 256 + threadIdx.x) >> 6;
  int lane = threadIdx.x & 63;
  const float* hr = hdnp + (size_t)wave * 512;
  float s0 = 0.f, s1 = 0.f, s2 = 0.f;
#pragma unroll
  for (int u = 0; u < 8; ++u) {
    int hcol = u * 64 + lane;
    float vv = hr[hcol] + rb1[hcol];
    float gl = 0.5f * vv * (1.0f + erff(vv * 0.70710678118654752f));
    s0 += gl * rw2[hcol * 3 + 0];
    s1 += gl * rw2[hcol * 3 + 1];
    s2 += gl * rw2[hcol * 3 + 2];
  }
#pragma unroll
  for (int off = 32; off; off >>= 1) {
    s0 += __shfl_xor(s0, off);
    s1 += __shfl_xor(s1, off);
    s2 += __shfl_xor(s2, off);
  }
  if (lane == 0) {
    float a = s0 + rb2[0], bb = s1 + rb2[1], c = s2 + rb2[2];
    float m = fmaxf(fmaxf(a, bb), c);
    float e0 = expf(a - m), e1 = expf(bb - m), e2 = expf(c - m);
    float inv = 1.0f / (e0 + e1 + e2);
    lam[(size_t)wave * 3 + 0] = e0 * inv;
    lam[(size_t)wave * 3 + 1] = e1 * inv;
    lam[(size_t)wave * 3 + 2] = e2 * inv;
  }
}

// ---------------- fused dual-stream MFMA flash attention ----------------
// One block = 128 q-rows of one (b,h), 4 waves x 32 rows, KV tile 64, both
// memory streams (s=0: x-derived K1/V1; s=1: l2-derived K2/V2). Q frags from
// global (read once). Output: mixedb bf16 = lam0*A0 + lam1*A1 + lam2*v3.
// Block remap: pair p and p+256 get q-blocks j and 7-j (constant work sum).
__global__ __launch_bounds__(256) void attn_fused_kernel(
    const short* __restrict__ q, int ldq,
    const short* __restrict__ k1, const short* __restrict__ v1, int ld1,
    const short* __restrict__ k2, const short* __restrict__ v2, int ld2,
    const float* __restrict__ lam, const float* __restrict__ v3,
    short* __restrict__ mixedb) {
  __shared__ short Ks[2][64][64];   // [stream][key][dh], k8 XOR swizzle
  __shared__ short Vt[2][64][64];   // [stream][dh][key], dword XOR swizzle
  __shared__ short Ps[4][32][64];   // per-wave P, kt XOR swizzle

  int bid = blockIdx.x;
  int half = bid >> 8, p = bid & 255;
  int bh = p & 63;
  int j = p >> 6;
  int qb = half ? (7 - j) : j;
  int b = bh >> 4, h = bh & 15;
  int q0 = qb * 128;
  int tid = threadIdx.x;
  int w = tid >> 6, l = tid & 63;
  int lg = l >> 4, ll = l & 15;

  int qw0 = q0 + w * 32;
  // Q fragments straight from global (each row read exactly once per kernel)
  bf16x8 qf[2][2];
#pragma unroll
  for (int rf = 0; rf < 2; ++rf) {
    const short* qr = q + (size_t)(b * T_ + qw0 + rf * 16 + ll) * ldq + h * DH_;
    qf[rf][0] = *(const bf16x8*)&qr[lg * 8];
    qf[rf][1] = *(const bf16x8*)&qr[32 + lg * 8];
  }

  float m_[2][2][4], l_[2][2][4];
  f32x4 o[2][2][4];
#pragma unroll
  for (int s = 0; s < 2; ++s)
#pragma unroll
    for (int rf = 0; rf < 2; ++rf)
#pragma unroll
      for (int r = 0; r < 4; ++r) {
        m_[s][rf][r] = -1e30f;
        l_[s][rf][r] = 0.f;
        o[s][rf][r] = (f32x4){0.f, 0.f, 0.f, 0.f};  // (reuse r as db below)
      }

  const float SC = 0.125f * 1.44269504f;  // scale * log2(e)
  int nt = (q0 >> 6) + 2;
  for (int t64 = 0; t64 < nt; ++t64) {
    int key0 = t64 * 64;
    __syncthreads();
    // ---- stage K and V (both streams) ----
#pragma unroll
    for (int s = 0; s < 2; ++s) {
      const short* kp = s ? k2 : k1;
      const short* vp = s ? v2 : v1;
      int ld = s ? ld2 : ld1;
#pragma unroll
      for (int it = 0; it < 2; ++it) {
        int e = it * 256 + tid;
        int r = e >> 3, c8 = e & 7;
        *(bf16x8*)&Ks[s][r][((c8 ^ (r & 7)) << 3)] =
            *(const bf16x8*)&kp[(size_t)(b * T_ + key0 + r) * ld + h * DH_ + c8 * 8];
      }
      {
        int kp2 = tid >> 3, c8 = tid & 7;
        size_t gi = (size_t)(b * T_ + key0 + kp2 * 2) * ld + h * DH_ + c8 * 8;
        bf16x8 va = *(const bf16x8*)&vp[gi];
        bf16x8 vb = *(const bf16x8*)&vp[gi + ld];
        unsigned int* Vtd = (unsigned int*)Vt[s];
#pragma unroll
        for (int jj = 0; jj < 8; ++jj) {
          int dh = c8 * 8 + jj;
          int X = ((dh ^ (dh >> 3)) & 7) << 2;
          Vtd[dh * 32 + (kp2 ^ X)] =
              ((unsigned int)(unsigned short)va[jj]) |
              (((unsigned int)(unsigned short)vb[jj]) << 16);
        }
      }
    }
    __syncthreads();
    if (key0 > qw0 + 31) continue;  // wave fully masked (uniform per wave)

#pragma unroll
    for (int s = 0; s < 2; ++s) {
      // ---- QK^T: 16 MFMA ----
      f32x4 c[2][4];
#pragma unroll
      for (int rf = 0; rf < 2; ++rf)
#pragma unroll
        for (int kt = 0; kt < 4; ++kt) c[rf][kt] = (f32x4){0.f, 0.f, 0.f, 0.f};
      __builtin_amdgcn_s_setprio(1);
#pragma unroll
      for (int kt = 0; kt < 4; ++kt) {
        int kr = kt * 16 + ll;
        bf16x8 kfa = *(const bf16x8*)&Ks[s][kr][((lg ^ (kr & 7)) << 3)];
        bf16x8 kfb = *(const bf16x8*)&Ks[s][kr][(((4 + lg) ^ (kr & 7)) << 3)];
#pragma unroll
        for (int rf = 0; rf < 2; ++rf) {
          c[rf][kt] = __builtin_amdgcn_mfma_f32_16x16x32_bf16(qf[rf][0], kfa, c[rf][kt], 0, 0, 0);
          c[rf][kt] = __builtin_amdgcn_mfma_f32_16x16x32_bf16(qf[rf][1], kfb, c[rf][kt], 0, 0, 0);
        }
      }
      __builtin_amdgcn_s_setprio(0);

      // ---- online softmax (exp2 domain) + P write ----
#pragma unroll
      for (int rf = 0; rf < 2; ++rf) {
#pragma unroll
        for (int r = 0; r < 4; ++r) {
          int grow = qw0 + rf * 16 + lg * 4 + r;
          float sv[4];
#pragma unroll
          for (int kt = 0; kt < 4; ++kt) {
            float sc = c[rf][kt][r] * SC;
            sv[kt] = (key0 + kt * 16 + ll > grow) ? -1e30f : sc;
          }
          float mx = fmaxf(fmaxf(sv[0], sv[1]), fmaxf(sv[2], sv[3]));
          mx = fmaxf(mx, __shfl_xor(mx, 1));
          mx = fmaxf(mx, __shfl_xor(mx, 2));
          mx = fmaxf(mx, __shfl_xor(mx, 4));
          mx = fmaxf(mx, __shfl_xor(mx, 8));
          float nm = fmaxf(m_[s][rf][r], mx);
          float al = exp2f(m_[s][rf][r] - nm);
          m_[s][rf][r] = nm;
          int prow = rf * 16 + lg * 4 + r;
          float rs = 0.f;
#pragma unroll
          for (int kt = 0; kt < 4; ++kt) {
            float pv = exp2f(sv[kt] - nm);
            rs += pv;
            Ps[w][prow][((kt ^ lg) << 4) + ll] = f2b(pv);
          }
          rs += __shfl_xor(rs, 1);
          rs += __shfl_xor(rs, 2);
          rs += __shfl_xor(rs, 4);
          rs += __shfl_xor(rs, 8);
          l_[s][rf][r] = l_[s][rf][r] * al + rs;
#pragma unroll
          for (int db = 0; db < 4; ++db) o[s][rf][db][r] *= al;
        }
      }
      asm volatile("s_waitcnt lgkmcnt(0)" ::: "memory");
      __builtin_amdgcn_sched_barrier(0);

      // ---- PV: 16 MFMA ----
      __builtin_amdgcn_s_setprio(1);
#pragma unroll
      for (int ks = 0; ks < 2; ++ks) {
        int pswz = (ks * 32 + lg * 8) ^ ((ll >> 2) << 4);
        bf16x8 pf0 = *(const bf16x8*)&Ps[w][ll][pswz];
        bf16x8 pf1 = *(const bf16x8*)&Ps[w][16 + ll][pswz];
        const unsigned int* Vtd = (const unsigned int*)Vt[s];
#pragma unroll
        for (int db = 0; db < 4; ++db) {
          int dh = db * 16 + ll;
          int X = ((dh ^ (dh >> 3)) & 7) << 2;
          bf16x8 vf = *(const bf16x8*)&Vtd[dh * 32 + ((ks * 16 + lg * 4) ^ X)];
          o[s][0][db] = __builtin_amdgcn_mfma_f32_16x16x32_bf16(pf0, vf, o[s][0][db], 0, 0, 0);
          o[s][1][db] = __builtin_amdgcn_mfma_f32_16x16x32_bf16(pf1, vf, o[s][1][db], 0, 0, 0);
        }
      }
      __builtin_amdgcn_s_setprio(0);
      __builtin_amdgcn_sched_barrier(0);  // keep next stream's Ps writes behind PV reads
    }
  }

  // ---- epilogue: lam0*o0/l0 + lam1*o1/l1 + lam2*v3 -> bf16 mixed ----
#pragma unroll
  for (int rf = 0; rf < 2; ++rf)
#pragma unroll
    for (int r = 0; r < 4; ++r) {
      int grow = qw0 + rf * 16 + lg * 4 + r;
      const float* lr = lam + (size_t)(b * T_ + grow) * 3;
      float w0 = lr[0] / l_[0][rf][r];
      float w1 = lr[1] / l_[1][rf][r];
      float w2 = lr[2];
#pragma unroll
      for (int db = 0; db < 4; ++db) {
        int dcol = h * DH_ + db * 16 + ll;
        float val = w0 * o[0][rf][db][r] + w1 * o[1][rf][db][r] +
                    w2 * v3[(b << 10) + dcol];
        mixedb[(size_t)(b * T_ + grow) * D_ + dcol] = f2b(val);
      }
    }
}

extern "C" void kernel_launch(void* const* d_in, const int* in_sizes, int n_in,
                              void* d_out, int out_size, void* d_ws, size_t ws_size,
                              hipStream_t stream) {
  const float* x = (const float*)d_in[0];
  const float* l3m = (const float*)d_in[1];
  const float* wq = (const float*)d_in[2];
  const float* wk = (const float*)d_in[3];
  const float* wv = (const float*)d_in[4];
  const float* wo = (const float*)d_in[5];
  const float* rw1 = (const float*)d_in[6];
  const float* rb1 = (const float*)d_in[7];
  const float* rw2 = (const float*)d_in[8];
  const float* rb2 = (const float*)d_in[9];

  float* out = (float*)d_out;
  float* lam = out + (size_t)M_ * D_;  // output tail: [4096,3]

  float* ws = (float*)d_ws;
  // R0: l2 f32 (16MB) early; QKV bf16 (24MB) later (l2 dead after ema_fix)
  float* l2 = ws;
  short* QKV = (short*)ws;              // [4096][3072] bf16
  float* hdnp = ws + 6291456;           // 2M floats (after 24MB R0)
  float* v3 = ws + 8388608;
  float* gbuf = ws + 8392704;
  short* sb = (short*)(ws + 8458240);
  short* xb = sb;                       // 4M shorts
  short* l2b = sb + 4194304;            // 4M
  short* KV2 = sb + 8388608;            // 8M: [4096][2048]
  short* mixedb = sb + 16777216;        // 4M
  short* wqkvT = sb + 20971520;         // 3M: [3072][1024]
  short* woT = sb + 24117248;           // 1M
  short* rw1T = sb + 25165824;          // 512K

  dim3 blk(256);

  // weight transpose+convert (wq|wk|wv concat), x convert
  transpose_w_kernel<<<dim3(32, 32, 5), blk, 0, stream>>>(
      wq, wk, wv, wo, rw1,
      wqkvT, wqkvT + 1024 * 1024, wqkvT + 2048 * 1024, woT, rw1T);
  cvt_bf16_kernel<<<4096, blk, 0, stream>>>(x, xb);

  // EMA l2 -> l2b (bf16); l2-f32 dead afterwards
  ema_chunk_kernel<<<256, blk, 0, stream>>>(x, l2);
  ema_carry_kernel<<<16, blk, 0, stream>>>(l2, gbuf);
  ema_fix_kernel<<<16384, blk, 0, stream>>>(l2, gbuf, l2b);

  // [q|k1|v1] = xb @ wqkvT^T  (N=3072, overwrites R0)
  gemm_bt<<<dim3(24, 32), blk, 0, stream>>>(xb, 1024, wqkvT, (float*)nullptr, QKV, 3072, 1024);
  // [k2|v2] = l2b @ [wk|wv]^T (N=2048)
  gemm_bt<<<dim3(16, 32), blk, 0, stream>>>(l2b, 1024, wqkvT + 1024 * 1024,
                                            (float*)nullptr, KV2, 2048, 1024);

  // router: hdnp = q @ rw1T (q strided inside QKV)
  gemm_bt<<<dim3(4, 32), blk, 0, stream>>>(QKV, 3072, rw1T, hdnp, (short*)nullptr, 512, 1024);
  router_kernel<<<1024, blk, 0, stream>>>(hdnp, rb1, rw2, rb2, lam);

  // l3 value vector
  v3_kernel<<<16, blk, 0, stream>>>(l3m, wv, v3);

  // fused dual-stream attention -> mixedb (bf16)
  attn_fused_kernel<<<512, blk, 0, stream>>>(QKV, 3072,
                                             QKV + 1024, QKV + 2048, 3072,
                                             KV2, KV2 + 1024, 2048,
                                             lam, v3, mixedb);

  // out = mixedb @ woT
  gemm_bt<<<dim3(8, 32), blk, 0, stream>>>(mixedb, 1024, woT, out, (short*)nullptr, 1024, 1024);
}

// Round 6
// 288.003 us; speedup vs baseline: 7.6991x; 1.1606x over previous
//
#include <hip/hip_runtime.h>
#include <hip/hip_bf16.h>
#include <math.h>

// MKAFullAttention: B=4, T=1024, D=1024, H=16, DH=64, BETA=0.9
// Round 6: attention occupancy + softmax-VALU cut.
//   - QBLK=64 (1024 blocks, 4 blocks/CU), wave owns 16 rows.
//   - row-sum (l) computed by an extra PV MFMA against an all-ones B-frag
//     (replaces 4x shfl_xor sum reduce).
//   - everything else unchanged from R5.

#define B_ 4
#define T_ 1024
#define D_ 1024
#define H_ 16
#define DH_ 64
#define M_ 4096

#define ECH 64
#define NCH 16

typedef __attribute__((ext_vector_type(8))) short bf16x8;
typedef __attribute__((ext_vector_type(4))) short s16x4;
typedef __attribute__((ext_vector_type(4))) float f32x4;

__device__ inline short f2b(float f) {
  __hip_bfloat16 h = __float2bfloat16(f);
  return *reinterpret_cast<short*>(&h);
}

__device__ inline void gload_lds16(const short* g, short* l) {
  __builtin_amdgcn_global_load_lds(
      (const __attribute__((address_space(1))) unsigned int*)g,
      (__attribute__((address_space(3))) unsigned int*)l, 16, 0, 0);
}

// ---------------- EMA chunked scan ----------------
__global__ __launch_bounds__(256) void ema_chunk_kernel(const float* __restrict__ x,
                                                        float* __restrict__ l2) {
  int idx = blockIdx.x * 256 + threadIdx.x;  // B*NCH*D = 65536
  int d = idx & (D_ - 1);
  int ch = (idx >> 10) & (NCH - 1);
  int b = idx >> 14;
  const float* xp = x + (size_t)(b * T_ + ch * ECH) * D_ + d;
  float* yp = l2 + (size_t)(b * T_ + ch * ECH) * D_ + d;
  float y = 0.f;
#pragma unroll 4
  for (int t = 0; t < ECH; ++t) {
    y = 0.9f * y + 0.1f * xp[t * D_];
    yp[t * D_] = y;
  }
}

__global__ __launch_bounds__(256) void ema_carry_kernel(const float* __restrict__ l2,
                                                        float* __restrict__ g) {
  int idx = blockIdx.x * 256 + threadIdx.x;  // B*D = 4096
  int d = idx & (D_ - 1);
  int b = idx >> 10;
  const float b64 = 0.0011790184577739f;  // 0.9^64
  float G = 0.f;
  for (int ch = 0; ch < NCH; ++ch) {
    g[(size_t)(b * NCH + ch) * D_ + d] = G;
    float lf = l2[(size_t)(b * T_ + ch * ECH + ECH - 1) * D_ + d];
    G = lf + b64 * G;
  }
}

// fix + convert to bf16 (l2 f32 is dead after this kernel)
__global__ __launch_bounds__(256) void ema_fix_kernel(const float* __restrict__ l2,
                                                      const float* __restrict__ g,
                                                      short* __restrict__ l2b) {
  int idx = blockIdx.x * 256 + threadIdx.x;  // 4M
  int d = idx & (D_ - 1);
  int t = (idx >> 10) & (T_ - 1);
  int b = idx >> 20;
  int ch = t >> 6;
  int off = t & (ECH - 1);
  float G = g[(size_t)(b * NCH + ch) * D_ + d];
  float p9 = exp2f((float)(off + 1) * -0.15200309344504997f);  // 0.9^(off+1)
  l2b[idx] = f2b(l2[idx] + p9 * G);
}

// ---------------- f32 -> bf16 convert (vectorized) ----------------
__global__ __launch_bounds__(256) void cvt_bf16_kernel(const float* __restrict__ in,
                                                       short* __restrict__ out) {
  int idx = blockIdx.x * 256 + threadIdx.x;
  float4 v = ((const float4*)in)[idx];
  s16x4 o;
  o[0] = f2b(v.x); o[1] = f2b(v.y); o[2] = f2b(v.z); o[3] = f2b(v.w);
  ((s16x4*)out)[idx] = o;
}

// ---------------- weight transpose + convert: Wt[n][k] = bf16(W[k][n]) ----------------
__global__ __launch_bounds__(256) void transpose_w_kernel(
    const float* __restrict__ w0, const float* __restrict__ w1,
    const float* __restrict__ w2, const float* __restrict__ w3,
    const float* __restrict__ w4,
    short* __restrict__ t0, short* __restrict__ t1, short* __restrict__ t2,
    short* __restrict__ t3, short* __restrict__ t4) {
  int z = blockIdx.z;
  const float* W = (z == 0) ? w0 : (z == 1) ? w1 : (z == 2) ? w2 : (z == 3) ? w3 : w4;
  short* Wt = (z == 0) ? t0 : (z == 1) ? t1 : (z == 2) ? t2 : (z == 3) ? t3 : t4;
  int cols = (z == 4) ? 512 : 1024;
  int c0 = blockIdx.x * 32, r0 = blockIdx.y * 32;
  if (c0 >= cols) return;
  __shared__ float tile[32][33];
  int tc = threadIdx.x & 31, tr8 = threadIdx.x >> 5;
#pragma unroll
  for (int i = 0; i < 4; ++i)
    tile[tr8 + i * 8][tc] = W[(size_t)(r0 + tr8 + i * 8) * cols + c0 + tc];
  __syncthreads();
#pragma unroll
  for (int i = 0; i < 4; ++i) {
    int rr = tr8 + i * 8;
    Wt[(size_t)(c0 + rr) * 1024 + r0 + tc] = f2b(tile[tc][rr]);
  }
}

// ---------------- bf16 MFMA GEMM: C[M,N] = A[M,K](lda) @ Bt[N,K]^T ----------------
__global__ __launch_bounds__(256) void gemm_bt(const short* __restrict__ A, int lda,
                                               const short* __restrict__ Bt,
                                               float* __restrict__ Cf,
                                               short* __restrict__ Cb,
                                               int Ndim, int Kdim) {
  __shared__ short As[128 * 64];
  __shared__ short Bs[128 * 64];
  int tid = threadIdx.x;
  int w = tid >> 6, l = tid & 63;
  int lg = l >> 4, ll = l & 15;
  int wr = w >> 1, wc = w & 1;
  int row0 = blockIdx.y * 128, col0 = blockIdx.x * 128;

  f32x4 acc[4][4];
#pragma unroll
  for (int m = 0; m < 4; ++m)
#pragma unroll
    for (int n = 0; n < 4; ++n) acc[m][n] = (f32x4){0.f, 0.f, 0.f, 0.f};

  for (int k0 = 0; k0 < Kdim; k0 += 64) {
    __syncthreads();
#pragma unroll
    for (int it = 0; it < 4; ++it) {
      int s = it * 256 + w * 64 + l;
      int r = s >> 3;
      int c = (s & 7) ^ (r & 7);  // pre-swizzled source (linear LDS dest)
      gload_lds16(A + (size_t)(row0 + r) * lda + k0 + c * 8, &As[(it * 256 + w * 64) * 8]);
      gload_lds16(Bt + (size_t)(col0 + r) * Kdim + k0 + c * 8, &Bs[(it * 256 + w * 64) * 8]);
    }
    __syncthreads();
#pragma unroll
    for (int ks = 0; ks < 2; ++ks) {
      bf16x8 af[4], bfr[4];
#pragma unroll
      for (int m = 0; m < 4; ++m) {
        int r = wr * 64 + m * 16 + ll;
        af[m] = *(const bf16x8*)&As[r * 64 + (((ks * 4 + lg) ^ (r & 7)) << 3)];
      }
#pragma unroll
      for (int n = 0; n < 4; ++n) {
        int r = wc * 64 + n * 16 + ll;
        bfr[n] = *(const bf16x8*)&Bs[r * 64 + (((ks * 4 + lg) ^ (r & 7)) << 3)];
      }
#pragma unroll
      for (int m = 0; m < 4; ++m)
#pragma unroll
        for (int n = 0; n < 4; ++n)
          acc[m][n] = __builtin_amdgcn_mfma_f32_16x16x32_bf16(af[m], bfr[n], acc[m][n], 0, 0, 0);
    }
  }
#pragma unroll
  for (int m = 0; m < 4; ++m) {
    int gr = row0 + wr * 64 + m * 16 + lg * 4;
#pragma unroll
    for (int n = 0; n < 4; ++n) {
      int gc = col0 + wc * 64 + n * 16 + ll;
#pragma unroll
      for (int r = 0; r < 4; ++r) {
        float vv = acc[m][n][r];
        if (Cf) Cf[(size_t)(gr + r) * Ndim + gc] = vv;
        if (Cb) Cb[(size_t)(gr + r) * Ndim + gc] = f2b(vv);
      }
    }
  }
}

// ---------------- v3 = l3_memory @ wv  ([B,1024], f32) ----------------
__global__ __launch_bounds__(256) void v3_kernel(const float* __restrict__ l3,
                                                 const float* __restrict__ wv,
                                                 float* __restrict__ v3) {
  int idx = blockIdx.x * 256 + threadIdx.x;  // B*D = 4096
  int b = idx >> 10;
  int col = idx & 1023;
  const float* xr = l3 + (size_t)b * D_;
  float acc = 0.f;
#pragma unroll 8
  for (int k = 0; k < D_; ++k) acc += xr[k] * wv[(size_t)k * D_ + col];
  v3[idx] = acc;
}

// ---------------- router ----------------
__global__ __launch_bounds__(256) void router_kernel(const float* __restrict__ hdnp,
                                                     const float* __restrict__ rb1,
                                                     const float* __restrict__ rw2,
                                                     const float* __restrict__ rb2,
                                                     float* __restrict__ lam) {
  int wave = (blockIdx.x * 256 + threadIdx.x) >> 6;
  int lane = threadIdx.x & 63;
  const float* hr = hdnp + (size_t)wave * 512;
  float s0 = 0.f, s1 = 0.f, s2 = 0.f;
#pragma unroll
  for (int u = 0; u < 8; ++u) {
    int hcol = u * 64 + lane;
    float vv = hr[hcol] + rb1[hcol];
    float gl = 0.5f * vv * (1.0f + erff(vv * 0.70710678118654752f));
    s0 += gl * rw2[hcol * 3 + 0];
    s1 += gl * rw2[hcol * 3 + 1];
    s2 += gl * rw2[hcol * 3 + 2];
  }
#pragma unroll
  for (int off = 32; off; off >>= 1) {
    s0 += __shfl_xor(s0, off);
    s1 += __shfl_xor(s1, off);
    s2 += __shfl_xor(s2, off);
  }
  if (lane == 0) {
    float a = s0 + rb2[0], bb = s1 + rb2[1], c = s2 + rb2[2];
    float m = fmaxf(fmaxf(a, bb), c);
    float e0 = expf(a - m), e1 = expf(bb - m), e2 = expf(c - m);
    float inv = 1.0f / (e0 + e1 + e2);
    lam[(size_t)wave * 3 + 0] = e0 * inv;
    lam[(size_t)wave * 3 + 1] = e1 * inv;
    lam[(size_t)wave * 3 + 2] = e2 * inv;
  }
}

// ---------------- fused dual-stream MFMA flash attention ----------------
// One block = 64 q-rows of one (b,h); 4 waves x 16 rows. KV tile 64, both
// streams. l-sum via extra PV MFMA vs all-ones B-frag. Pair-sum remap:
// halves pair qb j with 15-j (constant 17 tiles per pair).
__global__ __launch_bounds__(256) void attn_fused_kernel(
    const short* __restrict__ q, int ldq,
    const short* __restrict__ k1, const short* __restrict__ v1, int ld1,
    const short* __restrict__ k2, const short* __restrict__ v2, int ld2,
    const float* __restrict__ lam, const float* __restrict__ v3,
    short* __restrict__ mixedb) {
  __shared__ short Ks[2][64][64];   // [stream][key][dh], k8 XOR swizzle
  __shared__ short Vt[2][64][64];   // [stream][dh][key], dword XOR swizzle
  __shared__ short Ps[4][16][64];   // per-wave P, kt XOR swizzle

  int bid = blockIdx.x;
  int half = bid >> 9, p = bid & 511;
  int bh = p & 63;
  int j = p >> 6;
  int qb = half ? (15 - j) : j;
  int b = bh >> 4, h = bh & 15;
  int q0 = qb * 64;
  int tid = threadIdx.x;
  int w = tid >> 6, l = tid & 63;
  int lg = l >> 4, ll = l & 15;

  int qw0 = q0 + w * 16;
  // Q fragments straight from global (each row read exactly once)
  bf16x8 qf[2];
  {
    const short* qr = q + (size_t)(b * T_ + qw0 + ll) * ldq + h * DH_;
    qf[0] = *(const bf16x8*)&qr[lg * 8];
    qf[1] = *(const bf16x8*)&qr[32 + lg * 8];
  }

  float m_[2][4];
  f32x4 o[2][4];   // [stream][db]
  f32x4 ol[2];     // [stream] row-sum accumulator (any col)
#pragma unroll
  for (int s = 0; s < 2; ++s) {
#pragma unroll
    for (int r = 0; r < 4; ++r) m_[s][r] = -1e30f;
#pragma unroll
    for (int db = 0; db < 4; ++db) o[s][db] = (f32x4){0.f, 0.f, 0.f, 0.f};
    ol[s] = (f32x4){0.f, 0.f, 0.f, 0.f};
  }

  // all-ones bf16 B-fragment (1.0 = 0x3F80)
  bf16x8 ones;
#pragma unroll
  for (int jj = 0; jj < 8; ++jj) ones[jj] = (short)0x3F80;

  const float SC = 0.125f * 1.44269504f;  // scale * log2(e)
  int nt = qb + 1;
  for (int t64 = 0; t64 < nt; ++t64) {
    int key0 = t64 * 64;
    __syncthreads();
    // ---- stage K and V (both streams) ----
#pragma unroll
    for (int s = 0; s < 2; ++s) {
      const short* kp = s ? k2 : k1;
      const short* vp = s ? v2 : v1;
      int ld = s ? ld2 : ld1;
#pragma unroll
      for (int it = 0; it < 2; ++it) {
        int e = it * 256 + tid;
        int r = e >> 3, c8 = e & 7;
        *(bf16x8*)&Ks[s][r][((c8 ^ (r & 7)) << 3)] =
            *(const bf16x8*)&kp[(size_t)(b * T_ + key0 + r) * ld + h * DH_ + c8 * 8];
      }
      {
        int kp2 = tid >> 3, c8 = tid & 7;
        size_t gi = (size_t)(b * T_ + key0 + kp2 * 2) * ld + h * DH_ + c8 * 8;
        bf16x8 va = *(const bf16x8*)&vp[gi];
        bf16x8 vb = *(const bf16x8*)&vp[gi + ld];
        unsigned int* Vtd = (unsigned int*)Vt[s];
#pragma unroll
        for (int jj = 0; jj < 8; ++jj) {
          int dh = c8 * 8 + jj;
          int X = ((dh ^ (dh >> 3)) & 7) << 2;
          Vtd[dh * 32 + (kp2 ^ X)] =
              ((unsigned int)(unsigned short)va[jj]) |
              (((unsigned int)(unsigned short)vb[jj]) << 16);
        }
      }
    }
    __syncthreads();
    if (key0 > qw0 + 15) continue;  // wave fully masked (uniform per wave)

#pragma unroll
    for (int s = 0; s < 2; ++s) {
      // ---- QK^T: 8 MFMA ----
      f32x4 c[4];
#pragma unroll
      for (int kt = 0; kt < 4; ++kt) c[kt] = (f32x4){0.f, 0.f, 0.f, 0.f};
      __builtin_amdgcn_s_setprio(1);
#pragma unroll
      for (int kt = 0; kt < 4; ++kt) {
        int kr = kt * 16 + ll;
        bf16x8 kfa = *(const bf16x8*)&Ks[s][kr][((lg ^ (kr & 7)) << 3)];
        bf16x8 kfb = *(const bf16x8*)&Ks[s][kr][(((4 + lg) ^ (kr & 7)) << 3)];
        c[kt] = __builtin_amdgcn_mfma_f32_16x16x32_bf16(qf[0], kfa, c[kt], 0, 0, 0);
        c[kt] = __builtin_amdgcn_mfma_f32_16x16x32_bf16(qf[1], kfb, c[kt], 0, 0, 0);
      }
      __builtin_amdgcn_s_setprio(0);

      // ---- online softmax (exp2 domain) + P write; sum deferred to MFMA ----
#pragma unroll
      for (int r = 0; r < 4; ++r) {
        int grow = qw0 + lg * 4 + r;
        float sv[4];
#pragma unroll
        for (int kt = 0; kt < 4; ++kt) {
          float sc = c[kt][r] * SC;
          sv[kt] = (key0 + kt * 16 + ll > grow) ? -1e30f : sc;
        }
        float mx = fmaxf(fmaxf(sv[0], sv[1]), fmaxf(sv[2], sv[3]));
        mx = fmaxf(mx, __shfl_xor(mx, 1));
        mx = fmaxf(mx, __shfl_xor(mx, 2));
        mx = fmaxf(mx, __shfl_xor(mx, 4));
        mx = fmaxf(mx, __shfl_xor(mx, 8));
        float nm = fmaxf(m_[s][r], mx);
        float al = exp2f(m_[s][r] - nm);
        m_[s][r] = nm;
        int prow = lg * 4 + r;
#pragma unroll
        for (int kt = 0; kt < 4; ++kt) {
          float pv = exp2f(sv[kt] - nm);
          Ps[w][prow][((kt ^ lg) << 4) + ll] = f2b(pv);
        }
        ol[s][r] *= al;
#pragma unroll
        for (int db = 0; db < 4; ++db) o[s][db][r] *= al;
      }
      asm volatile("s_waitcnt lgkmcnt(0)" ::: "memory");
      __builtin_amdgcn_sched_barrier(0);

      // ---- PV: 8 MFMA + 2 for row-sum ----
      __builtin_amdgcn_s_setprio(1);
#pragma unroll
      for (int ks = 0; ks < 2; ++ks) {
        int pswz = (ks * 32 + lg * 8) ^ ((ll >> 2) << 4);
        bf16x8 pf = *(const bf16x8*)&Ps[w][ll][pswz];
        const unsigned int* Vtd = (const unsigned int*)Vt[s];
        ol[s] = __builtin_amdgcn_mfma_f32_16x16x32_bf16(pf, ones, ol[s], 0, 0, 0);
#pragma unroll
        for (int db = 0; db < 4; ++db) {
          int dh = db * 16 + ll;
          int X = ((dh ^ (dh >> 3)) & 7) << 2;
          bf16x8 vf = *(const bf16x8*)&Vtd[dh * 32 + ((ks * 16 + lg * 4) ^ X)];
          o[s][db] = __builtin_amdgcn_mfma_f32_16x16x32_bf16(pf, vf, o[s][db], 0, 0, 0);
        }
      }
      __builtin_amdgcn_s_setprio(0);
      __builtin_amdgcn_sched_barrier(0);  // keep next stream's Ps writes behind PV reads
    }
  }

  // ---- epilogue: lam0*o0/l0 + lam1*o1/l1 + lam2*v3 -> bf16 mixed ----
#pragma unroll
  for (int r = 0; r < 4; ++r) {
    int grow = qw0 + lg * 4 + r;
    const float* lr = lam + (size_t)(b * T_ + grow) * 3;
    float w0 = lr[0] / ol[0][r];
    float w1 = lr[1] / ol[1][r];
    float w2 = lr[2];
#pragma unroll
    for (int db = 0; db < 4; ++db) {
      int dcol = h * DH_ + db * 16 + ll;
      float val = w0 * o[0][db][r] + w1 * o[1][db][r] + w2 * v3[(b << 10) + dcol];
      mixedb[(size_t)(b * T_ + grow) * D_ + dcol] = f2b(val);
    }
  }
}

extern "C" void kernel_launch(void* const* d_in, const int* in_sizes, int n_in,
                              void* d_out, int out_size, void* d_ws, size_t ws_size,
                              hipStream_t stream) {
  const float* x = (const float*)d_in[0];
  const float* l3m = (const float*)d_in[1];
  const float* wq = (const float*)d_in[2];
  const float* wk = (const float*)d_in[3];
  const float* wv = (const float*)d_in[4];
  const float* wo = (const float*)d_in[5];
  const float* rw1 = (const float*)d_in[6];
  const float* rb1 = (const float*)d_in[7];
  const float* rw2 = (const float*)d_in[8];
  const float* rb2 = (const float*)d_in[9];

  float* out = (float*)d_out;
  float* lam = out + (size_t)M_ * D_;  // output tail: [4096,3]

  float* ws = (float*)d_ws;
  // R0: l2 f32 (16MB) early; QKV bf16 (24MB) later (l2 dead after ema_fix)
  float* l2 = ws;
  short* QKV = (short*)ws;              // [4096][3072] bf16
  float* hdnp = ws + 6291456;           // 2M floats (after 24MB R0)
  float* v3 = ws + 8388608;
  float* gbuf = ws + 8392704;
  short* sb = (short*)(ws + 8458240);
  short* xb = sb;                       // 4M shorts
  short* l2b = sb + 4194304;            // 4M
  short* KV2 = sb + 8388608;            // 8M: [4096][2048]
  short* mixedb = sb + 16777216;        // 4M
  short* wqkvT = sb + 20971520;         // 3M: [3072][1024]
  short* woT = sb + 24117248;           // 1M
  short* rw1T = sb + 25165824;          // 512K

  dim3 blk(256);

  // weight transpose+convert (wq|wk|wv concat), x convert
  transpose_w_kernel<<<dim3(32, 32, 5), blk, 0, stream>>>(
      wq, wk, wv, wo, rw1,
      wqkvT, wqkvT + 1024 * 1024, wqkvT + 2048 * 1024, woT, rw1T);
  cvt_bf16_kernel<<<4096, blk, 0, stream>>>(x, xb);

  // EMA l2 -> l2b (bf16); l2-f32 dead afterwards
  ema_chunk_kernel<<<256, blk, 0, stream>>>(x, l2);
  ema_carry_kernel<<<16, blk, 0, stream>>>(l2, gbuf);
  ema_fix_kernel<<<16384, blk, 0, stream>>>(l2, gbuf, l2b);

  // [q|k1|v1] = xb @ wqkvT^T  (N=3072, overwrites R0)
  gemm_bt<<<dim3(24, 32), blk, 0, stream>>>(xb, 1024, wqkvT, (float*)nullptr, QKV, 3072, 1024);
  // [k2|v2] = l2b @ [wk|wv]^T (N=2048)
  gemm_bt<<<dim3(16, 32), blk, 0, stream>>>(l2b, 1024, wqkvT + 1024 * 1024,
                                            (float*)nullptr, KV2, 2048, 1024);

  // router: hdnp = q @ rw1T (q strided inside QKV)
  gemm_bt<<<dim3(4, 32), blk, 0, stream>>>(QKV, 3072, rw1T, hdnp, (short*)nullptr, 512, 1024);
  router_kernel<<<1024, blk, 0, stream>>>(hdnp, rb1, rw2, rb2, lam);

  // l3 value vector
  v3_kernel<<<16, blk, 0, stream>>>(l3m, wv, v3);

  // fused dual-stream attention -> mixedb (bf16)
  attn_fused_kernel<<<1024, blk, 0, stream>>>(QKV, 3072,
                                              QKV + 1024, QKV + 2048, 3072,
                                              KV2, KV2 + 1024, 2048,
                                              lam, v3, mixedb);

  // out = mixedb @ woT
  gemm_bt<<<dim3(8, 32), blk, 0, stream>>>(mixedb, 1024, woT, out, (short*)nullptr, 1024, 1024);
}

// Round 8
// 251.992 us; speedup vs baseline: 8.7994x; 1.1429x over previous
//
#include <hip/hip_runtime.h>
#include <hip/hip_bf16.h>
#include <math.h>

// MKAFullAttention: B=4, T=1024, D=1024, H=16, DH=64, BETA=0.9
// Round 8: fix R7's gemm_bt<64> bug (NF must be 4 — each wave covers all 64
//          cols; NF=NB/32 left cols 32..63 unwritten => poisoned lam/out).
//          All other R7 changes kept unchanged.
//   - l3 stream analytic: attend(l3) = broadcast(l3@wv).

#define B_ 4
#define T_ 1024
#define D_ 1024
#define H_ 16
#define DH_ 64
#define M_ 4096

#define ECH 64
#define NCH 16

typedef __attribute__((ext_vector_type(8))) short bf16x8;
typedef __attribute__((ext_vector_type(4))) short s16x4;
typedef __attribute__((ext_vector_type(4))) float f32x4;

__device__ inline short f2b(float f) {
  __hip_bfloat16 h = __float2bfloat16(f);
  return *reinterpret_cast<short*>(&h);
}

__device__ inline void gload_lds16(const short* g, short* l) {
  __builtin_amdgcn_global_load_lds(
      (const __attribute__((address_space(1))) unsigned int*)g,
      (__attribute__((address_space(3))) unsigned int*)l, 16, 0, 0);
}

// ---------------- EMA chunked scan (+ fused x->bf16 convert) ----------------
__global__ __launch_bounds__(256) void ema_chunk_kernel(const float* __restrict__ x,
                                                        float* __restrict__ l2,
                                                        short* __restrict__ xb) {
  int idx = blockIdx.x * 256 + threadIdx.x;  // B*NCH*D = 65536
  int d = idx & (D_ - 1);
  int ch = (idx >> 10) & (NCH - 1);
  int b = idx >> 14;
  const float* xp = x + (size_t)(b * T_ + ch * ECH) * D_ + d;
  float* yp = l2 + (size_t)(b * T_ + ch * ECH) * D_ + d;
  short* xbp = xb + (size_t)(b * T_ + ch * ECH) * D_ + d;
  float y = 0.f;
#pragma unroll 4
  for (int t = 0; t < ECH; ++t) {
    float xv = xp[t * D_];
    y = 0.9f * y + 0.1f * xv;
    yp[t * D_] = y;
    xbp[t * D_] = f2b(xv);
  }
}

__global__ __launch_bounds__(256) void ema_carry_kernel(const float* __restrict__ l2,
                                                        float* __restrict__ g) {
  int idx = blockIdx.x * 256 + threadIdx.x;  // B*D = 4096
  int d = idx & (D_ - 1);
  int b = idx >> 10;
  const float b64 = 0.0011790184577739f;  // 0.9^64
  float G = 0.f;
  for (int ch = 0; ch < NCH; ++ch) {
    g[(size_t)(b * NCH + ch) * D_ + d] = G;
    float lf = l2[(size_t)(b * T_ + ch * ECH + ECH - 1) * D_ + d];
    G = lf + b64 * G;
  }
}

// fix + convert to bf16 (l2 f32 is dead after this kernel)
__global__ __launch_bounds__(256) void ema_fix_kernel(const float* __restrict__ l2,
                                                      const float* __restrict__ g,
                                                      short* __restrict__ l2b) {
  int idx = blockIdx.x * 256 + threadIdx.x;  // 4M
  int d = idx & (D_ - 1);
  int t = (idx >> 10) & (T_ - 1);
  int b = idx >> 20;
  int ch = t >> 6;
  int off = t & (ECH - 1);
  float G = g[(size_t)(b * NCH + ch) * D_ + d];
  float p9 = exp2f((float)(off + 1) * -0.15200309344504997f);  // 0.9^(off+1)
  l2b[idx] = f2b(l2[idx] + p9 * G);
}

// ---------------- weight transpose + convert: Wt[n][k] = bf16(W[k][n]) ----------------
__global__ __launch_bounds__(256) void transpose_w_kernel(
    const float* __restrict__ w0, const float* __restrict__ w1,
    const float* __restrict__ w2, const float* __restrict__ w3,
    const float* __restrict__ w4,
    short* __restrict__ t0, short* __restrict__ t1, short* __restrict__ t2,
    short* __restrict__ t3, short* __restrict__ t4) {
  int z = blockIdx.z;
  const float* W = (z == 0) ? w0 : (z == 1) ? w1 : (z == 2) ? w2 : (z == 3) ? w3 : w4;
  short* Wt = (z == 0) ? t0 : (z == 1) ? t1 : (z == 2) ? t2 : (z == 3) ? t3 : t4;
  int cols = (z == 4) ? 512 : 1024;
  int c0 = blockIdx.x * 32, r0 = blockIdx.y * 32;
  if (c0 >= cols) return;
  __shared__ float tile[32][33];
  int tc = threadIdx.x & 31, tr8 = threadIdx.x >> 5;
#pragma unroll
  for (int i = 0; i < 4; ++i)
    tile[tr8 + i * 8][tc] = W[(size_t)(r0 + tr8 + i * 8) * cols + c0 + tc];
  __syncthreads();
#pragma unroll
  for (int i = 0; i < 4; ++i) {
    int rr = tr8 + i * 8;
    Wt[(size_t)(c0 + rr) * 1024 + r0 + tc] = f2b(tile[tc][rr]);
  }
}

// ---------------- bf16 MFMA GEMM: C[M,N] = A[M,K](lda) @ Bt[N,K]^T ----------------
// 128xNB tile (NB=128 or 64), BK=64, 4 waves, global_load_lds 16B, XOR k8-swizzle.
// Per-wave output: NB=128 -> 64x64 (2x2 wave grid); NB=64 -> 32x64 (4x1).
template <int NB>
__global__ __launch_bounds__(256) void gemm_bt(const short* __restrict__ A, int lda,
                                               const short* __restrict__ Bt,
                                               float* __restrict__ Cf,
                                               short* __restrict__ Cb,
                                               int Ndim, int Kdim) {
  __shared__ short As[128 * 64];
  __shared__ short Bs[NB * 64];
  constexpr int NW = NB / 64;              // col-wave count (2 or 1)
  constexpr int NF = 4;                    // n-frags per wave: always 64 cols
  constexpr int MF = (NW == 2) ? 4 : 2;    // m-frags per wave
  int tid = threadIdx.x;
  int w = tid >> 6, l = tid & 63;
  int lg = l >> 4, ll = l & 15;
  int wr = (NW == 2) ? (w >> 1) : w;       // row wave: 0..1 or 0..3
  int wc = (NW == 2) ? (w & 1) : 0;
  int row0 = blockIdx.y * 128, col0 = blockIdx.x * NB;

  f32x4 acc[MF][NF];
#pragma unroll
  for (int m = 0; m < MF; ++m)
#pragma unroll
    for (int n = 0; n < NF; ++n) acc[m][n] = (f32x4){0.f, 0.f, 0.f, 0.f};

  for (int k0 = 0; k0 < Kdim; k0 += 64) {
    __syncthreads();
#pragma unroll
    for (int it = 0; it < 4; ++it) {
      int s = it * 256 + w * 64 + l;
      int r = s >> 3;
      int c = (s & 7) ^ (r & 7);  // pre-swizzled source (linear LDS dest)
      gload_lds16(A + (size_t)(row0 + r) * lda + k0 + c * 8, &As[(it * 256 + w * 64) * 8]);
    }
#pragma unroll
    for (int it = 0; it < NB / 32; ++it) {
      int s = it * 256 + w * 64 + l;
      int r = s >> 3;
      int c = (s & 7) ^ (r & 7);
      gload_lds16(Bt + (size_t)(col0 + r) * Kdim + k0 + c * 8, &Bs[(it * 256 + w * 64) * 8]);
    }
    __syncthreads();
#pragma unroll
    for (int ks = 0; ks < 2; ++ks) {
      bf16x8 af[MF], bfr[NF];
#pragma unroll
      for (int m = 0; m < MF; ++m) {
        int r = wr * (MF * 16) + m * 16 + ll;
        af[m] = *(const bf16x8*)&As[r * 64 + (((ks * 4 + lg) ^ (r & 7)) << 3)];
      }
#pragma unroll
      for (int n = 0; n < NF; ++n) {
        int r = wc * 64 + n * 16 + ll;
        bfr[n] = *(const bf16x8*)&Bs[r * 64 + (((ks * 4 + lg) ^ (r & 7)) << 3)];
      }
#pragma unroll
      for (int m = 0; m < MF; ++m)
#pragma unroll
        for (int n = 0; n < NF; ++n)
          acc[m][n] = __builtin_amdgcn_mfma_f32_16x16x32_bf16(af[m], bfr[n], acc[m][n], 0, 0, 0);
    }
  }
#pragma unroll
  for (int m = 0; m < MF; ++m) {
    int gr = row0 + wr * (MF * 16) + m * 16 + lg * 4;
#pragma unroll
    for (int n = 0; n < NF; ++n) {
      int gc = col0 + wc * 64 + n * 16 + ll;
#pragma unroll
      for (int r = 0; r < 4; ++r) {
        float vv = acc[m][n][r];
        if (Cf) Cf[(size_t)(gr + r) * Ndim + gc] = vv;
        if (Cb) Cb[(size_t)(gr + r) * Ndim + gc] = f2b(vv);
      }
    }
  }
}

// ---------------- merged QKV + KV2 GEMM (1280 blocks) ----------------
__global__ __launch_bounds__(256) void gemm_dual(const short* __restrict__ xb,
                                                 const short* __restrict__ l2b,
                                                 const short* __restrict__ wqkvT,
                                                 short* __restrict__ QKV,
                                                 short* __restrict__ KV2) {
  const short* A;
  const short* Bt;
  short* Cb;
  int Ndim, col0;
  int bx = blockIdx.x;  // 0..39
  if (bx < 24) {
    A = xb; Bt = wqkvT; Cb = QKV; Ndim = 3072; col0 = bx * 128;
  } else {
    A = l2b; Bt = wqkvT + 1024 * 1024; Cb = KV2; Ndim = 2048; col0 = (bx - 24) * 128;
  }
  __shared__ short As[128 * 64];
  __shared__ short Bs[128 * 64];
  int tid = threadIdx.x;
  int w = tid >> 6, l = tid & 63;
  int lg = l >> 4, ll = l & 15;
  int wr = w >> 1, wc = w & 1;
  int row0 = blockIdx.y * 128;

  f32x4 acc[4][4];
#pragma unroll
  for (int m = 0; m < 4; ++m)
#pragma unroll
    for (int n = 0; n < 4; ++n) acc[m][n] = (f32x4){0.f, 0.f, 0.f, 0.f};

  for (int k0 = 0; k0 < 1024; k0 += 64) {
    __syncthreads();
#pragma unroll
    for (int it = 0; it < 4; ++it) {
      int s = it * 256 + w * 64 + l;
      int r = s >> 3;
      int c = (s & 7) ^ (r & 7);
      gload_lds16(A + (size_t)(row0 + r) * 1024 + k0 + c * 8, &As[(it * 256 + w * 64) * 8]);
      gload_lds16(Bt + (size_t)(col0 + r) * 1024 + k0 + c * 8, &Bs[(it * 256 + w * 64) * 8]);
    }
    __syncthreads();
#pragma unroll
    for (int ks = 0; ks < 2; ++ks) {
      bf16x8 af[4], bfr[4];
#pragma unroll
      for (int m = 0; m < 4; ++m) {
        int r = wr * 64 + m * 16 + ll;
        af[m] = *(const bf16x8*)&As[r * 64 + (((ks * 4 + lg) ^ (r & 7)) << 3)];
      }
#pragma unroll
      for (int n = 0; n < 4; ++n) {
        int r = wc * 64 + n * 16 + ll;
        bfr[n] = *(const bf16x8*)&Bs[r * 64 + (((ks * 4 + lg) ^ (r & 7)) << 3)];
      }
#pragma unroll
      for (int m = 0; m < 4; ++m)
#pragma unroll
        for (int n = 0; n < 4; ++n)
          acc[m][n] = __builtin_amdgcn_mfma_f32_16x16x32_bf16(af[m], bfr[n], acc[m][n], 0, 0, 0);
    }
  }
#pragma unroll
  for (int m = 0; m < 4; ++m) {
    int gr = row0 + wr * 64 + m * 16 + lg * 4;
#pragma unroll
    for (int n = 0; n < 4; ++n) {
      int gc = col0 + wc * 64 + n * 16 + ll;
#pragma unroll
      for (int r = 0; r < 4; ++r)
        Cb[(size_t)(gr + r) * Ndim + gc] = f2b(acc[m][n][r]);
    }
  }
}

// ---------------- v3 = l3_memory @ wv  ([B,1024], f32) ----------------
__global__ __launch_bounds__(256) void v3_kernel(const float* __restrict__ l3,
                                                 const float* __restrict__ wv,
                                                 float* __restrict__ v3) {
  int idx = blockIdx.x * 256 + threadIdx.x;  // B*D = 4096
  int b = idx >> 10;
  int col = idx & 1023;
  const float* xr = l3 + (size_t)b * D_;
  float acc = 0.f;
#pragma unroll 8
  for (int k = 0; k < D_; ++k) acc += xr[k] * wv[(size_t)k * D_ + col];
  v3[idx] = acc;
}

// ---------------- router ----------------
__global__ __launch_bounds__(256) void router_kernel(const float* __restrict__ hdnp,
                                                     const float* __restrict__ rb1,
                                                     const float* __restrict__ rw2,
                                                     const float* __restrict__ rb2,
                                                     float* __restrict__ lam) {
  int wave = (blockIdx.x * 256 + threadIdx.x) >> 6;
  int lane = threadIdx.x & 63;
  const float* hr = hdnp + (size_t)wave * 512;
  float s0 = 0.f, s1 = 0.f, s2 = 0.f;
#pragma unroll
  for (int u = 0; u < 8; ++u) {
    int hcol = u * 64 + lane;
    float vv = hr[hcol] + rb1[hcol];
    float gl = 0.5f * vv * (1.0f + erff(vv * 0.70710678118654752f));
    s0 += gl * rw2[hcol * 3 + 0];
    s1 += gl * rw2[hcol * 3 + 1];
    s2 += gl * rw2[hcol * 3 + 2];
  }
#pragma unroll
  for (int off = 32; off; off >>= 1) {
    s0 += __shfl_xor(s0, off);
    s1 += __shfl_xor(s1, off);
    s2 += __shfl_xor(s2, off);
  }
  if (lane == 0) {
    float a = s0 + rb2[0], bb = s1 + rb2[1], c = s2 + rb2[2];
    float m = fmaxf(fmaxf(a, bb), c);
    float e0 = expf(a - m), e1 = expf(bb - m), e2 = expf(c - m);
    float inv = 1.0f / (e0 + e1 + e2);
    lam[(size_t)wave * 3 + 0] = e0 * inv;
    lam[(size_t)wave * 3 + 1] = e1 * inv;
    lam[(size_t)wave * 3 + 2] = e2 * inv;
  }
}

// ---------------- fused dual-stream MFMA flash attention ----------------
// One block = 64 q-rows of one (b,h); 4 waves x 16 rows. KV tile 64, both
// streams. l-sum via ones-MFMA. K staged with global_load_lds (pre-swizzled
// source). Defer-max (THR=8, exp2 domain). Interior tiles skip causal mask.
__global__ __launch_bounds__(256) void attn_fused_kernel(
    const short* __restrict__ q, int ldq,
    const short* __restrict__ k1, const short* __restrict__ v1, int ld1,
    const short* __restrict__ k2, const short* __restrict__ v2, int ld2,
    const float* __restrict__ lam, const float* __restrict__ v3,
    short* __restrict__ mixedb) {
  __shared__ short Ks[2][64][64];   // [stream][key][dh], k8 XOR swizzle (linear dest)
  __shared__ short Vt[2][64][64];   // [stream][dh][key], dword XOR swizzle
  __shared__ short Ps[4][16][64];   // per-wave P, kt XOR swizzle

  int bid = blockIdx.x;
  int half = bid >> 9, p = bid & 511;
  int bh = p & 63;
  int j = p >> 6;
  int qb = half ? (15 - j) : j;
  int b = bh >> 4, h = bh & 15;
  int q0 = qb * 64;
  int tid = threadIdx.x;
  int w = tid >> 6, l = tid & 63;
  int lg = l >> 4, ll = l & 15;

  int qw0 = q0 + w * 16;
  // Q fragments straight from global (each row read exactly once)
  bf16x8 qf[2];
  {
    const short* qr = q + (size_t)(b * T_ + qw0 + ll) * ldq + h * DH_;
    qf[0] = *(const bf16x8*)&qr[lg * 8];
    qf[1] = *(const bf16x8*)&qr[32 + lg * 8];
  }

  float m_[2][4];
  f32x4 o[2][4];   // [stream][db]
  f32x4 ol[2];     // [stream] row-sum accumulator
#pragma unroll
  for (int s = 0; s < 2; ++s) {
#pragma unroll
    for (int r = 0; r < 4; ++r) m_[s][r] = -1e30f;
#pragma unroll
    for (int db = 0; db < 4; ++db) o[s][db] = (f32x4){0.f, 0.f, 0.f, 0.f};
    ol[s] = (f32x4){0.f, 0.f, 0.f, 0.f};
  }

  bf16x8 ones;
#pragma unroll
  for (int jj = 0; jj < 8; ++jj) ones[jj] = (short)0x3F80;  // 1.0bf16

  const float SC = 0.125f * 1.44269504f;  // scale * log2(e)
  int nt = qb + 1;
  for (int t64 = 0; t64 < nt; ++t64) {
    int key0 = t64 * 64;
    __syncthreads();
    // ---- stage K (global_load_lds, pre-swizzled source) and V (pack-transpose) ----
#pragma unroll
    for (int s = 0; s < 2; ++s) {
      const short* kp = s ? k2 : k1;
      const short* vp = s ? v2 : v1;
      int ld = s ? ld2 : ld1;
#pragma unroll
      for (int it = 0; it < 2; ++it) {
        int e = it * 256 + w * 64 + l;
        int r = e >> 3;
        int cs = (e & 7) ^ (r & 7);
        gload_lds16(kp + (size_t)(b * T_ + key0 + r) * ld + h * DH_ + cs * 8,
                    (short*)Ks[s] + (it * 256 + w * 64) * 8);
      }
      {
        int kp2 = tid >> 3, c8 = tid & 7;
        size_t gi = (size_t)(b * T_ + key0 + kp2 * 2) * ld + h * DH_ + c8 * 8;
        bf16x8 va = *(const bf16x8*)&vp[gi];
        bf16x8 vb = *(const bf16x8*)&vp[gi + ld];
        unsigned int* Vtd = (unsigned int*)Vt[s];
#pragma unroll
        for (int jj = 0; jj < 8; ++jj) {
          int dh = c8 * 8 + jj;
          int X = ((dh ^ (dh >> 3)) & 7) << 2;
          Vtd[dh * 32 + (kp2 ^ X)] =
              ((unsigned int)(unsigned short)va[jj]) |
              (((unsigned int)(unsigned short)vb[jj]) << 16);
        }
      }
    }
    __syncthreads();
    if (key0 > qw0 + 15) continue;  // wave fully masked (uniform per wave)

#pragma unroll
    for (int s = 0; s < 2; ++s) {
      // ---- QK^T: 8 MFMA ----
      f32x4 c[4];
#pragma unroll
      for (int kt = 0; kt < 4; ++kt) c[kt] = (f32x4){0.f, 0.f, 0.f, 0.f};
      __builtin_amdgcn_s_setprio(1);
#pragma unroll
      for (int kt = 0; kt < 4; ++kt) {
        int kr = kt * 16 + ll;
        bf16x8 kfa = *(const bf16x8*)&Ks[s][kr][((lg ^ (kr & 7)) << 3)];
        bf16x8 kfb = *(const bf16x8*)&Ks[s][kr][(((4 + lg) ^ (kr & 7)) << 3)];
        c[kt] = __builtin_amdgcn_mfma_f32_16x16x32_bf16(qf[0], kfa, c[kt], 0, 0, 0);
        c[kt] = __builtin_amdgcn_mfma_f32_16x16x32_bf16(qf[1], kfb, c[kt], 0, 0, 0);
      }
      __builtin_amdgcn_s_setprio(0);

      // ---- scores (interior tiles skip mask) ----
      float sv[4][4];
      if (key0 + 63 <= qw0) {
#pragma unroll
        for (int r = 0; r < 4; ++r)
#pragma unroll
          for (int kt = 0; kt < 4; ++kt) sv[r][kt] = c[kt][r] * SC;
      } else {
#pragma unroll
        for (int r = 0; r < 4; ++r) {
          int grow = qw0 + lg * 4 + r;
#pragma unroll
          for (int kt = 0; kt < 4; ++kt) {
            float t = c[kt][r] * SC;
            sv[r][kt] = (key0 + kt * 16 + ll > grow) ? -1e30f : t;
          }
        }
      }

      // ---- row max + defer-max rescale ----
      float mx[4];
#pragma unroll
      for (int r = 0; r < 4; ++r) {
        float m0 = fmaxf(fmaxf(sv[r][0], sv[r][1]), fmaxf(sv[r][2], sv[r][3]));
        m0 = fmaxf(m0, __shfl_xor(m0, 1));
        m0 = fmaxf(m0, __shfl_xor(m0, 2));
        m0 = fmaxf(m0, __shfl_xor(m0, 4));
        m0 = fmaxf(m0, __shfl_xor(m0, 8));
        mx[r] = m0;
      }
      int grew = 0;
#pragma unroll
      for (int r = 0; r < 4; ++r) grew |= (mx[r] > m_[s][r] + 8.f) ? 1 : 0;
      if (__any(grew)) {
#pragma unroll
        for (int r = 0; r < 4; ++r) {
          float nm = fmaxf(m_[s][r], mx[r]);
          float al = exp2f(m_[s][r] - nm);
          m_[s][r] = nm;
          ol[s][r] *= al;
#pragma unroll
          for (int db = 0; db < 4; ++db) o[s][db][r] *= al;
        }
      }

      // ---- P = exp2(sv - m), write to LDS ----
#pragma unroll
      for (int r = 0; r < 4; ++r) {
        float mr = m_[s][r];
        int prow = lg * 4 + r;
#pragma unroll
        for (int kt = 0; kt < 4; ++kt) {
          float pv = exp2f(sv[r][kt] - mr);
          Ps[w][prow][((kt ^ lg) << 4) + ll] = f2b(pv);
        }
      }
      asm volatile("s_waitcnt lgkmcnt(0)" ::: "memory");
      __builtin_amdgcn_sched_barrier(0);

      // ---- PV: 8 MFMA + 2 for row-sum ----
      __builtin_amdgcn_s_setprio(1);
#pragma unroll
      for (int ks = 0; ks < 2; ++ks) {
        int pswz = (ks * 32 + lg * 8) ^ ((ll >> 2) << 4);
        bf16x8 pf = *(const bf16x8*)&Ps[w][ll][pswz];
        const unsigned int* Vtd = (const unsigned int*)Vt[s];
        ol[s] = __builtin_amdgcn_mfma_f32_16x16x32_bf16(pf, ones, ol[s], 0, 0, 0);
#pragma unroll
        for (int db = 0; db < 4; ++db) {
          int dh = db * 16 + ll;
          int X = ((dh ^ (dh >> 3)) & 7) << 2;
          bf16x8 vf = *(const bf16x8*)&Vtd[dh * 32 + ((ks * 16 + lg * 4) ^ X)];
          o[s][db] = __builtin_amdgcn_mfma_f32_16x16x32_bf16(pf, vf, o[s][db], 0, 0, 0);
        }
      }
      __builtin_amdgcn_s_setprio(0);
      __builtin_amdgcn_sched_barrier(0);  // keep next stream's Ps writes behind PV reads
    }
  }

  // ---- epilogue: lam0*o0/l0 + lam1*o1/l1 + lam2*v3 -> bf16 mixed ----
#pragma unroll
  for (int r = 0; r < 4; ++r) {
    int grow = qw0 + lg * 4 + r;
    const float* lr = lam + (size_t)(b * T_ + grow) * 3;
    float w0 = lr[0] / ol[0][r];
    float w1 = lr[1] / ol[1][r];
    float w2 = lr[2];
#pragma unroll
    for (int db = 0; db < 4; ++db) {
      int dcol = h * DH_ + db * 16 + ll;
      float val = w0 * o[0][db][r] + w1 * o[1][db][r] + w2 * v3[(b << 10) + dcol];
      mixedb[(size_t)(b * T_ + grow) * D_ + dcol] = f2b(val);
    }
  }
}

extern "C" void kernel_launch(void* const* d_in, const int* in_sizes, int n_in,
                              void* d_out, int out_size, void* d_ws, size_t ws_size,
                              hipStream_t stream) {
  const float* x = (const float*)d_in[0];
  const float* l3m = (const float*)d_in[1];
  const float* wq = (const float*)d_in[2];
  const float* wk = (const float*)d_in[3];
  const float* wv = (const float*)d_in[4];
  const float* wo = (const float*)d_in[5];
  const float* rw1 = (const float*)d_in[6];
  const float* rb1 = (const float*)d_in[7];
  const float* rw2 = (const float*)d_in[8];
  const float* rb2 = (const float*)d_in[9];

  float* out = (float*)d_out;
  float* lam = out + (size_t)M_ * D_;  // output tail: [4096,3]

  float* ws = (float*)d_ws;
  // R0: l2 f32 (16MB) early; QKV bf16 (24MB) later (l2 dead after gemm_dual start)
  float* l2 = ws;
  short* QKV = (short*)ws;              // [4096][3072] bf16
  float* hdnp = ws + 6291456;           // 2M floats (after 24MB R0)
  float* v3 = ws + 8388608;
  float* gbuf = ws + 8392704;
  short* sb = (short*)(ws + 8458240);
  short* xb = sb;                       // 4M shorts
  short* l2b = sb + 4194304;            // 4M
  short* KV2 = sb + 8388608;            // 8M: [4096][2048]
  short* mixedb = sb + 16777216;        // 4M
  short* wqkvT = sb + 20971520;         // 3M: [3072][1024]
  short* woT = sb + 24117248;           // 1M
  short* rw1T = sb + 25165824;          // 512K

  dim3 blk(256);

  // weight transpose+convert (wq|wk|wv concat)
  transpose_w_kernel<<<dim3(32, 32, 5), blk, 0, stream>>>(
      wq, wk, wv, wo, rw1,
      wqkvT, wqkvT + 1024 * 1024, wqkvT + 2048 * 1024, woT, rw1T);

  // EMA l2 -> l2b (bf16), fused x->xb convert
  ema_chunk_kernel<<<256, blk, 0, stream>>>(x, l2, xb);
  ema_carry_kernel<<<16, blk, 0, stream>>>(l2, gbuf);
  ema_fix_kernel<<<16384, blk, 0, stream>>>(l2, gbuf, l2b);

  // [q|k1|v1] = xb @ wqkvT^T (N=3072) and [k2|v2] = l2b @ [wk|wv]^T (N=2048)
  gemm_dual<<<dim3(40, 32), blk, 0, stream>>>(xb, l2b, wqkvT, QKV, KV2);

  // router: hdnp = q @ rw1T (q strided inside QKV), BN=64 -> 256 blocks
  gemm_bt<64><<<dim3(8, 32), blk, 0, stream>>>(QKV, 3072, rw1T, hdnp, (short*)nullptr, 512, 1024);
  router_kernel<<<1024, blk, 0, stream>>>(hdnp, rb1, rw2, rb2, lam);

  // l3 value vector
  v3_kernel<<<16, blk, 0, stream>>>(l3m, wv, v3);

  // fused dual-stream attention -> mixedb (bf16)
  attn_fused_kernel<<<1024, blk, 0, stream>>>(QKV, 3072,
                                              QKV + 1024, QKV + 2048, 3072,
                                              KV2, KV2 + 1024, 2048,
                                              lam, v3, mixedb);

  // out = mixedb @ woT, BN=64 -> 512 blocks
  gemm_bt<64><<<dim3(16, 32), blk, 0, stream>>>(mixedb, 1024, woT, out, (short*)nullptr, 1024, 1024);
}